// Round 3
// baseline (240.298 us; speedup 1.0000x reference)
//
#include <hip/hip_runtime.h>
#include <math.h>

#define BB 2
#define LL 2048
#define DIMM 1024
#define HH 16
#define DD 64
#define QKV_N 3072

typedef unsigned short u16;
typedef unsigned int u32;
typedef __attribute__((ext_vector_type(8))) short short8;   // 8 x bf16
typedef __attribute__((ext_vector_type(4))) float f32x4;

__device__ __forceinline__ float bf2f(u16 h) {
    unsigned u = ((unsigned)h) << 16;
    return __uint_as_float(u);
}
__device__ __forceinline__ u16 f2bf(float f) {
    unsigned u = __float_as_uint(f);
    u += 0x7fffu + ((u >> 16) & 1u);   // round-to-nearest-even
    return (u16)(u >> 16);
}
// pack two f32 -> (bf16(hi)<<16)|bf16(lo), round-half-up
__device__ __forceinline__ u32 pack_bf2(float lo, float hi) {
    u32 a = __float_as_uint(hi) + 0x8000u;
    u32 b = __float_as_uint(lo) + 0x8000u;
    return __builtin_amdgcn_perm(a, b, 0x07060302u);
}
// async global->LDS, 16B per lane; LDS dst is wave-uniform base + lane*16
__device__ __forceinline__ void gload16(const u16* g, u16* l) {
    __builtin_amdgcn_global_load_lds(
        (const __attribute__((address_space(1))) void*)g,
        (__attribute__((address_space(3))) void*)l, 16, 0, 0);
}

// ---------------- f32 -> bf16 convert (x) -------------------------------------
__global__ __launch_bounds__(256) void convx(
    const float* __restrict__ X, u16* __restrict__ Xb)
{
    int i = (blockIdx.x * 256 + threadIdx.x) * 8;
    float4 a = *(const float4*)&X[i];
    float4 b = *(const float4*)&X[i + 4];
    u16 t[8] = {f2bf(a.x), f2bf(a.y), f2bf(a.z), f2bf(a.w),
                f2bf(b.x), f2bf(b.y), f2bf(b.z), f2bf(b.w)};
    *(uint4*)&Xb[i] = *(uint4*)t;
}

// ---------------- f32 [K,N] -> bf16 [N,K] transpose-convert -------------------
__global__ __launch_bounds__(256) void convt(
    const float* __restrict__ W, u16* __restrict__ Wt, int K, int N)
{
    __shared__ u16 s[64][72];
    const int tid = threadIdx.x;
    const int k0 = blockIdx.x * 64, n0 = blockIdx.y * 64;
#pragma unroll
    for (int t = 0; t < 16; ++t) {
        int flat = t * 256 + tid;
        int kk = flat >> 6, nn = flat & 63;
        s[nn][kk] = f2bf(W[(size_t)(k0 + kk) * N + n0 + nn]);
    }
    __syncthreads();
#pragma unroll
    for (int t = 0; t < 2; ++t) {
        int chunk = t * 256 + tid;
        int nn = chunk >> 3, kc = chunk & 7;
        *(uint4*)&Wt[(size_t)(n0 + nn) * K + k0 + kc * 8] = *(uint4*)&s[nn][kc * 8];
    }
}

// ---------------- QKV GEMM (global_load_lds staging) + fused epilogues --------
// q tiles: RMSNorm + RoPE -> bf16 qkv rows (attn reads Q rows as B-operand).
// k tiles: RMSNorm + RoPE -> kpack in MFMA-fragment order:
//          kp[(((bh*32+kt)*4+nb)*2+c)*512 + lane*8 + j]
//            = K[token kt*64+16nb+(lane&15)][d = 32c + 8*((lane>>4)&3) + j]
// v tiles: -> vpack, fragment order for PV B-operand:
//          vp[same-block-shape] = V[key kt*64+32c+8*((lane>>4)&3)+j][d = 16nb+(lane&15)]
// Attn then loads any operand fragment as ONE coalesced dwordx4 at base+lane*16.
__global__ __launch_bounds__(256) void gemm_qkv(
    const u16* __restrict__ A, const u16* __restrict__ Bt,
    u16* __restrict__ C, u16* __restrict__ kp, u16* __restrict__ vp,
    const float* __restrict__ pe,
    const float* __restrict__ qs, const float* __restrict__ ks)
{
    __shared__ u16 smem[2 * 128 * 64];   // sA | sB
    u16* sA = smem;
    u16* sB = smem + 128 * 64;

    const int tid = threadIdx.x;
    const int wave = tid >> 6, lane = tid & 63;
    const int mIdx = lane & 15, quad = lane >> 4;
    const int wr = wave >> 1, wc = wave & 1;
    const int m0 = blockIdx.y * 128, n0 = blockIdx.x * 128;
    const int N = QKV_N, K = DIMM;
    const int lr = lane >> 3, lc = lane & 7;

    f32x4 acc[4][4];
#pragma unroll
    for (int a = 0; a < 4; ++a)
#pragma unroll
        for (int b = 0; b < 4; ++b) acc[a][b] = (f32x4){0.f, 0.f, 0.f, 0.f};

    for (int k0 = 0; k0 < K; k0 += 64) {
#pragma unroll
        for (int j = 0; j < 4; ++j) {
            int r0 = 32 * wave + 8 * j + lr;
            int kc = 8 * (lc ^ (r0 & 7));
            gload16(&A[(size_t)(m0 + r0) * K + k0 + kc], &sA[(32 * wave + 8 * j) * 64]);
            gload16(&Bt[(size_t)(n0 + r0) * K + k0 + kc], &sB[(32 * wave + 8 * j) * 64]);
        }
        __syncthreads();
#pragma unroll
        for (int ks2 = 0; ks2 < 2; ++ks2) {
            short8 af[4], bfr[4];
#pragma unroll
            for (int mt = 0; mt < 4; ++mt) {
                int Ra = 64 * wr + 16 * mt + mIdx;
                af[mt] = *(const short8*)&sA[Ra * 64 + 8 * ((ks2 * 4 + quad) ^ (Ra & 7))];
            }
#pragma unroll
            for (int nt = 0; nt < 4; ++nt) {
                int Rb = 64 * wc + 16 * nt + mIdx;
                bfr[nt] = *(const short8*)&sB[Rb * 64 + 8 * ((ks2 * 4 + quad) ^ (Rb & 7))];
            }
#pragma unroll
            for (int mt = 0; mt < 4; ++mt)
#pragma unroll
                for (int nt = 0; nt < 4; ++nt)
                    acc[mt][nt] = __builtin_amdgcn_mfma_f32_16x16x32_bf16(
                        af[mt], bfr[nt], acc[mt][nt], 0, 0, 0);
        }
        __syncthreads();
    }

    if (n0 >= 2048) {
        // ---- v region: direct store to vpack (fragment order, no LDS) ----
#pragma unroll
        for (int mt = 0; mt < 4; ++mt) {
            const int R0 = m0 + 64 * wr + 16 * mt + 4 * quad;   // token row of r=0
            const int bb = R0 >> 11;
            const int t0 = R0 & 2047;                            // key index, %4==0
#pragma unroll
            for (int nt = 0; nt < 4; ++nt) {
                const int hd = n0 - 2048 + 64 * wc + 16 * nt + mIdx;
                const int h = hd >> 6, d = hd & 63;
                const int bh = bb * 16 + h;
                const size_t blk =
                    ((size_t)(bh * 32 + (t0 >> 6)) * 4 + (d >> 4)) * 2 + ((t0 >> 5) & 1);
                const int ln = (d & 15) + 16 * ((t0 >> 3) & 3);
                uint2 pr;
                pr.x = pack_bf2(acc[mt][nt][0], acc[mt][nt][1]);
                pr.y = pack_bf2(acc[mt][nt][2], acc[mt][nt][3]);
                *(uint2*)&vp[blk * 512 + ln * 8 + (t0 & 7)] = pr;
            }
        }
    } else {
        // ---- q/k region: RMSNorm over head dim + RoPE; q prescaled log2e/8 --
        const bool isq = (n0 < 1024);
        const float* scv = isq ? qs : ks;
        const float pre = isq ? 0.18033688011112042f : 1.0f;
        float scl[4];
#pragma unroll
        for (int nt = 0; nt < 4; ++nt) scl[nt] = scv[16 * nt + mIdx];

#pragma unroll
        for (int mt = 0; mt < 4; ++mt) {
#pragma unroll
            for (int r = 0; r < 4; ++r) {
                float s = 0.f;
#pragma unroll
                for (int nt = 0; nt < 4; ++nt) {
                    float a = acc[mt][nt][r];
                    s += a * a;
                }
                s += __shfl_xor(s, 1);
                s += __shfl_xor(s, 2);
                s += __shfl_xor(s, 4);
                s += __shfl_xor(s, 8);
                float rn = rsqrtf(s * (1.f / 64.f) + 1e-6f);
                const int R = m0 + 64 * wr + 16 * mt + quad * 4 + r;   // = b*L + l
                const int bb = R >> 11, t = R & 2047;
                size_t peo = (size_t)R * 128;
#pragma unroll
                for (int nt = 0; nt < 4; ++nt) {
                    float v = acc[mt][nt][r] * rn * scl[nt];
                    float pp = __shfl_xor(v, 1);
                    float2 pw = *(const float2*)&pe[peo + 2 * (16 * nt + mIdx)];
                    float e  = (mIdx & 1) ? pp : v;
                    float od = (mIdx & 1) ? v : pp;
                    u16 val = f2bf((pw.x * e + pw.y * od) * pre);
                    if (isq) {
                        C[(size_t)R * N + n0 + 64 * wc + 16 * nt + mIdx] = val;
                    } else {
                        const int col = n0 - 1024 + 64 * wc + 16 * nt + mIdx;
                        const int h = col >> 6, d = col & 63;
                        const size_t blk =
                            ((size_t)((bb * 16 + h) * 32 + (t >> 6)) * 4 + ((t >> 4) & 3)) * 2
                            + (d >> 5);
                        kp[blk * 512 + ((t & 15) + 16 * ((d >> 3) & 3)) * 8 + (d & 7)] = val;
                    }
                }
            }
        }
    }
}

// ---------------- proj GEMM (global_load_lds staging, 64x128 tile) ------------
__global__ __launch_bounds__(256) void gemm_proj(
    const u16* __restrict__ A, const u16* __restrict__ Bt,
    const float* __restrict__ bias, float* __restrict__ C)
{
    __shared__ u16 sA[64 * 64];
    __shared__ u16 sB[128 * 64];

    const int tid = threadIdx.x;
    const int wave = tid >> 6, lane = tid & 63;
    const int mIdx = lane & 15, quad = lane >> 4;
    const int wr = wave >> 1, wc = wave & 1;   // 2x2 waves of 32x64
    const int m0 = blockIdx.y * 64, n0 = blockIdx.x * 128;
    const int N = DIMM, K = DIMM;
    const int lr = lane >> 3, lc = lane & 7;

    f32x4 acc[2][4];
#pragma unroll
    for (int a = 0; a < 2; ++a)
#pragma unroll
        for (int b = 0; b < 4; ++b) acc[a][b] = (f32x4){0.f, 0.f, 0.f, 0.f};

    for (int k0 = 0; k0 < K; k0 += 64) {
#pragma unroll
        for (int j = 0; j < 2; ++j) {       // A: 64 rows
            int r0 = 16 * wave + 8 * j + lr;
            int kc = 8 * (lc ^ (r0 & 7));
            gload16(&A[(size_t)(m0 + r0) * K + k0 + kc], &sA[(16 * wave + 8 * j) * 64]);
        }
#pragma unroll
        for (int j = 0; j < 4; ++j) {       // B: 128 rows
            int r0 = 32 * wave + 8 * j + lr;
            int kc = 8 * (lc ^ (r0 & 7));
            gload16(&Bt[(size_t)(n0 + r0) * K + k0 + kc], &sB[(32 * wave + 8 * j) * 64]);
        }
        __syncthreads();
#pragma unroll
        for (int ks2 = 0; ks2 < 2; ++ks2) {
            short8 af[2], bfr[4];
#pragma unroll
            for (int mt = 0; mt < 2; ++mt) {
                int Ra = 32 * wr + 16 * mt + mIdx;
                af[mt] = *(const short8*)&sA[Ra * 64 + 8 * ((ks2 * 4 + quad) ^ (Ra & 7))];
            }
#pragma unroll
            for (int nt = 0; nt < 4; ++nt) {
                int Rb = 64 * wc + 16 * nt + mIdx;
                bfr[nt] = *(const short8*)&sB[Rb * 64 + 8 * ((ks2 * 4 + quad) ^ (Rb & 7))];
            }
#pragma unroll
            for (int mt = 0; mt < 2; ++mt)
#pragma unroll
                for (int nt = 0; nt < 4; ++nt)
                    acc[mt][nt] = __builtin_amdgcn_mfma_f32_16x16x32_bf16(
                        af[mt], bfr[nt], acc[mt][nt], 0, 0, 0);
        }
        __syncthreads();
    }

#pragma unroll
    for (int mt = 0; mt < 2; ++mt)
#pragma unroll
        for (int r = 0; r < 4; ++r) {
            int row = m0 + 32 * wr + 16 * mt + quad * 4 + r;
#pragma unroll
            for (int nt = 0; nt < 4; ++nt) {
                int col = n0 + 64 * wc + 16 * nt + mIdx;
                C[(size_t)row * N + col] = acc[mt][nt][r] + bias[col];
            }
        }
}

// ---------------- flash attention: fragment-direct, barrier-free --------------
// R13: R12 post-mortem showed HBM/L2 latency was NOT the wall (FETCH 12 MB,
// hbm 3.5%, dur unchanged) — everything funnelled through the per-CU LDS pipe
// (~50% busy) under barrier lockstep. Fix: K/V operands load straight from
// L1/L2-resident fragment-packed buffers (one coalesced dwordx4 per fragment,
// base+lane*16) -> K/V traffic moves to the TA/L1 pipe, parallel to LDS which
// now carries only P. ZERO barriers: waves free-run and overlap phases.
// K register-double-buffered (next tile loads during current compute); V loads
// at iter top, consumed after the S^T phase covers their latency.
// l computed by MFMA against an all-ones fragment (no VALU adds, no shuffles).
__global__ __launch_bounds__(256, 2) void attn_mfma(
    const u16* __restrict__ qkv, const u16* __restrict__ kp,
    const u16* __restrict__ vp, u16* __restrict__ o)
{
    __shared__ u16 sP[128 * 64];

    const int tid = threadIdx.x;
    const int wave = tid >> 6;     // 0..3
    const int lane = tid & 63;
    const int mIdx = lane & 15;
    const int quad = lane >> 4;
    const int m7 = mIdx & 7;

    // XCD-chunked swizzle (512 blocks, 8 XCDs, 64 logical blocks per XCD)
    const int bid = ((blockIdx.x & 7) << 6) | (blockIdx.x >> 3);
    const int bh = bid >> 4;          // 16 q-tiles of 128 rows per (b,h)
    const int qt = bid & 15;
    const int b = bh >> 4, h = bh & 15;
    const int q0 = qt * 128;

    // fragment bases: tile kt at +kt*4096 u16; fragment f=nb*2+c at +f*512
    const u16* kbase = kp + (size_t)bh * 32 * 4096 + lane * 8;
    const u16* vbase = vp + (size_t)bh * 32 * 4096 + lane * 8;

    // Q fragments: 2 groups of 16 rows per wave
    short8 aq[2][2];
#pragma unroll
    for (int g = 0; g < 2; ++g) {
        const u16* qrow = qkv + (size_t)b * LL * QKV_N + h * 64
                          + (size_t)(q0 + 32 * wave + 16 * g + mIdx) * QKV_N;
        aq[g][0] = *(const short8*)&qrow[quad * 8];
        aq[g][1] = *(const short8*)&qrow[32 + quad * 8];
    }

    const short8 bones = {(short)0x3F80, (short)0x3F80, (short)0x3F80, (short)0x3F80,
                          (short)0x3F80, (short)0x3F80, (short)0x3F80, (short)0x3F80};

    float dummy;
    f32x4 Oacc[2][4];
    f32x4 lac[2];
#pragma unroll
    for (int g = 0; g < 2; ++g) {
        lac[g] = (f32x4){0.f, 0.f, 0.f, 0.f};
#pragma unroll
        for (int nb = 0; nb < 4; ++nb) Oacc[g][nb] = (f32x4){0.f, 0.f, 0.f, 0.f};
    }

    // P swizzle offsets (same proven pattern as R11/R12)
    const int o0 = 8 * (quad ^ m7);
    const int o1 = 8 * ((quad + 4) ^ m7);
    u16* sPr0 = &sP[(32 * wave + mIdx) * 64];
    u16* sPr1 = &sP[(32 * wave + 16 + mIdx) * 64];

    short8 kfA[8], kfB[8], vf[8];

    // prologue: K fragments of tile 0
#pragma unroll
    for (int f = 0; f < 8; ++f) kfA[f] = *(const short8*)&kbase[f * 512];

    auto body = [&](short8* KC, short8* KN, int kt) {
        const size_t tb = (size_t)kt * 4096;
        // V fragments for THIS tile (consumed after S^T phase)
#pragma unroll
        for (int f = 0; f < 8; ++f) vf[f] = *(const short8*)&vbase[tb + f * 512];
        // K fragments for NEXT tile (consumed next body)
        if (kt < 31) {
#pragma unroll
            for (int f = 0; f < 8; ++f) KN[f] = *(const short8*)&kbase[tb + 4096 + f * 512];
        }
        __builtin_amdgcn_sched_barrier(0);

        // ---- S^T strips: D[key][q] = mfma(A=K-frag, B=Q-frag) ----
#pragma unroll
        for (int nb = 0; nb < 4; ++nb) {
            const int pofs = (16 * nb + 4 * quad) ^ (8 * m7);
#pragma unroll
            for (int g = 0; g < 2; ++g) {
                f32x4 st = (f32x4){0.f, 0.f, 0.f, 0.f};
                st = __builtin_amdgcn_mfma_f32_16x16x32_bf16(KC[nb * 2 + 0], aq[g][0], st, 0, 0, 0);
                st = __builtin_amdgcn_mfma_f32_16x16x32_bf16(KC[nb * 2 + 1], aq[g][1], st, 0, 0, 0);
                float p0 = exp2f(st[0]), p1 = exp2f(st[1]);
                float p2 = exp2f(st[2]), p3 = exp2f(st[3]);
                uint2 wp;
                wp.x = pack_bf2(p0, p1);
                wp.y = pack_bf2(p2, p3);
                *(uint2*)&((g == 0 ? sPr0 : sPr1)[pofs]) = wp;
            }
        }
        // sP rows written and read by the same wave -> no barrier.
        short8 pa00 = *(const short8*)&sPr0[o0];
        short8 pa01 = *(const short8*)&sPr0[o1];
        short8 pa10 = *(const short8*)&sPr1[o0];
        short8 pa11 = *(const short8*)&sPr1[o1];

        // l accumulation via MFMA with all-ones B (no VALU adds, no shuffles)
        lac[0] = __builtin_amdgcn_mfma_f32_16x16x32_bf16(pa00, bones, lac[0], 0, 0, 0);
        lac[0] = __builtin_amdgcn_mfma_f32_16x16x32_bf16(pa01, bones, lac[0], 0, 0, 0);
        lac[1] = __builtin_amdgcn_mfma_f32_16x16x32_bf16(pa10, bones, lac[1], 0, 0, 0);
        lac[1] = __builtin_amdgcn_mfma_f32_16x16x32_bf16(pa11, bones, lac[1], 0, 0, 0);

        // ---- O += P @ V ----
        __builtin_amdgcn_s_setprio(1);
#pragma unroll
        for (int nb = 0; nb < 4; ++nb) {
            Oacc[0][nb] = __builtin_amdgcn_mfma_f32_16x16x32_bf16(pa00, vf[nb * 2 + 0], Oacc[0][nb], 0, 0, 0);
            Oacc[0][nb] = __builtin_amdgcn_mfma_f32_16x16x32_bf16(pa01, vf[nb * 2 + 1], Oacc[0][nb], 0, 0, 0);
            Oacc[1][nb] = __builtin_amdgcn_mfma_f32_16x16x32_bf16(pa10, vf[nb * 2 + 0], Oacc[1][nb], 0, 0, 0);
            Oacc[1][nb] = __builtin_amdgcn_mfma_f32_16x16x32_bf16(pa11, vf[nb * 2 + 1], Oacc[1][nb], 0, 0, 0);
        }
        __builtin_amdgcn_s_setprio(0);
    };

    for (int kt2 = 0; kt2 < 16; ++kt2) {
        body(kfA, kfB, 2 * kt2);
        body(kfB, kfA, 2 * kt2 + 1);
    }

    // epilogue: l for q-row quad*4+r (within group g) sits in lac[g][r] of
    // EVERY lane (all-ones B makes all columns equal) — no shuffles needed.
#pragma unroll
    for (int g = 0; g < 2; ++g)
#pragma unroll
        for (int r = 0; r < 4; ++r) {
            float linv = 1.f / lac[g][r];
            const int rowg = b * LL + q0 + 32 * wave + 16 * g + quad * 4 + r;
#pragma unroll
            for (int nb = 0; nb < 4; ++nb) {
                o[(size_t)rowg * DIMM + h * 64 + 16 * nb + mIdx] =
                    f2bf(Oacc[g][nb][r] * linv);
            }
        }
}

extern "C" void kernel_launch(void* const* d_in, const int* in_sizes, int n_in,
                              void* d_out, int out_size, void* d_ws, size_t ws_size,
                              hipStream_t stream) {
    const float* x       = (const float*)d_in[0];
    const float* pe      = (const float*)d_in[1];
    const float* w_qkv   = (const float*)d_in[2];
    const float* q_scale = (const float*)d_in[3];
    const float* k_scale = (const float*)d_in[4];
    const float* w_proj  = (const float*)d_in[5];
    const float* b_proj  = (const float*)d_in[6];
    float* out = (float*)d_out;

    char* ws = (char*)d_ws;
    u16* qkv    = (u16*)ws;  ws += (size_t)4096 * 3072 * 2;
    u16* o      = (u16*)ws;  ws += (size_t)4096 * 1024 * 2;
    u16* xb     = (u16*)ws;  ws += (size_t)4096 * 1024 * 2;
    u16* wqkvt  = (u16*)ws;  ws += (size_t)3072 * 1024 * 2;
    u16* wprojt = (u16*)ws;  ws += (size_t)1024 * 1024 * 2;
    u16* kpack  = (u16*)ws;  ws += (size_t)32 * 32 * 4096 * 2;   // 8.4 MB
    u16* vpack  = (u16*)ws;  ws += (size_t)32 * 32 * 4096 * 2;   // 8.4 MB

    // 0. conversions
    convx<<<(4096 * 1024) / (256 * 8), 256, 0, stream>>>(x, xb);
    convt<<<dim3(1024 / 64, QKV_N / 64), 256, 0, stream>>>(w_qkv, wqkvt, DIMM, QKV_N);
    convt<<<dim3(1024 / 64, 1024 / 64), 256, 0, stream>>>(w_proj, wprojt, DIMM, DIMM);

    // 1. fused QKV projection + RMSNorm/RoPE (q->qkv, k->kpack) + v->vpack
    gemm_qkv<<<dim3(QKV_N / 128, (BB * LL) / 128), 256, 0, stream>>>(
        xb, wqkvt, qkv, kpack, vpack, pe, q_scale, k_scale);

    // 2. attention (fragment-direct K/V, barrier-free)
    attn_mfma<<<BB * HH * (LL / 128), 256, 0, stream>>>(qkv, kpack, vpack, o);

    // 3. output projection + bias (f32 out)
    gemm_proj<<<dim3(DIMM / 128, (BB * LL) / 64), 256, 0, stream>>>(
        o, wprojt, b_proj, out);
}

// Round 4
// 236.696 us; speedup vs baseline: 1.0152x; 1.0152x over previous
//
#include <hip/hip_runtime.h>
#include <math.h>

#define BB 2
#define LL 2048
#define DIMM 1024
#define HH 16
#define DD 64
#define QKV_N 3072

typedef unsigned short u16;
typedef unsigned int u32;
typedef __attribute__((ext_vector_type(8))) short short8;   // 8 x bf16
typedef __attribute__((ext_vector_type(4))) float f32x4;

__device__ __forceinline__ float bf2f(u16 h) {
    unsigned u = ((unsigned)h) << 16;
    return __uint_as_float(u);
}
__device__ __forceinline__ u16 f2bf(float f) {
    unsigned u = __float_as_uint(f);
    u += 0x7fffu + ((u >> 16) & 1u);   // round-to-nearest-even
    return (u16)(u >> 16);
}
// pack two f32 -> (bf16(hi)<<16)|bf16(lo), round-half-up
__device__ __forceinline__ u32 pack_bf2(float lo, float hi) {
    u32 a = __float_as_uint(hi) + 0x8000u;
    u32 b = __float_as_uint(lo) + 0x8000u;
    return __builtin_amdgcn_perm(a, b, 0x07060302u);
}
// async global->LDS, 16B per lane; LDS dst is wave-uniform base + lane*16
__device__ __forceinline__ void gload16(const u16* g, u16* l) {
    __builtin_amdgcn_global_load_lds(
        (const __attribute__((address_space(1))) void*)g,
        (__attribute__((address_space(3))) void*)l, 16, 0, 0);
}

// ---------------- f32 -> bf16 convert (x) -------------------------------------
__global__ __launch_bounds__(256) void convx(
    const float* __restrict__ X, u16* __restrict__ Xb)
{
    int i = (blockIdx.x * 256 + threadIdx.x) * 8;
    float4 a = *(const float4*)&X[i];
    float4 b = *(const float4*)&X[i + 4];
    u16 t[8] = {f2bf(a.x), f2bf(a.y), f2bf(a.z), f2bf(a.w),
                f2bf(b.x), f2bf(b.y), f2bf(b.z), f2bf(b.w)};
    *(uint4*)&Xb[i] = *(uint4*)t;
}

// ---------------- f32 [K,N] -> bf16 [N,K] transpose-convert -------------------
__global__ __launch_bounds__(256) void convt(
    const float* __restrict__ W, u16* __restrict__ Wt, int K, int N)
{
    __shared__ u16 s[64][72];
    const int tid = threadIdx.x;
    const int k0 = blockIdx.x * 64, n0 = blockIdx.y * 64;
#pragma unroll
    for (int t = 0; t < 16; ++t) {
        int flat = t * 256 + tid;
        int kk = flat >> 6, nn = flat & 63;
        s[nn][kk] = f2bf(W[(size_t)(k0 + kk) * N + n0 + nn]);
    }
    __syncthreads();
#pragma unroll
    for (int t = 0; t < 2; ++t) {
        int chunk = t * 256 + tid;
        int nn = chunk >> 3, kc = chunk & 7;
        *(uint4*)&Wt[(size_t)(n0 + nn) * K + k0 + kc * 8] = *(uint4*)&s[nn][kc * 8];
    }
}

// ---------------- QKV GEMM (global_load_lds staging) + fused epilogues --------
// q tiles: RMSNorm + RoPE -> bf16 qkv rows (attn reads Q rows as B-operand).
// k tiles: RMSNorm + RoPE -> kpack in MFMA-fragment order.
// v tiles: -> vpack in MFMA-fragment order.
// R14: pack epilogues assemble the 32KB tile in LDS (scatter is cheap there)
// and store as 8 fully-coalesced uint4 per thread — R13's 64 scalar global
// scatter-stores/thread made gemm_qkv the top dispatch (95 us, pipes idle).
__global__ __launch_bounds__(256) void gemm_qkv(
    const u16* __restrict__ A, const u16* __restrict__ Bt,
    u16* __restrict__ C, u16* __restrict__ kp, u16* __restrict__ vp,
    const float* __restrict__ pe,
    const float* __restrict__ qs, const float* __restrict__ ks)
{
    __shared__ u16 smem[2 * 128 * 64];   // sA | sB; reused as pack-assembly buf
    u16* sA = smem;
    u16* sB = smem + 128 * 64;

    const int tid = threadIdx.x;
    const int wave = tid >> 6, lane = tid & 63;
    const int mIdx = lane & 15, quad = lane >> 4;
    const int wr = wave >> 1, wc = wave & 1;
    const int m0 = blockIdx.y * 128, n0 = blockIdx.x * 128;
    const int N = QKV_N, K = DIMM;
    const int lr = lane >> 3, lc = lane & 7;

    f32x4 acc[4][4];
#pragma unroll
    for (int a = 0; a < 4; ++a)
#pragma unroll
        for (int b = 0; b < 4; ++b) acc[a][b] = (f32x4){0.f, 0.f, 0.f, 0.f};

    for (int k0 = 0; k0 < K; k0 += 64) {
#pragma unroll
        for (int j = 0; j < 4; ++j) {
            int r0 = 32 * wave + 8 * j + lr;
            int kc = 8 * (lc ^ (r0 & 7));
            gload16(&A[(size_t)(m0 + r0) * K + k0 + kc], &sA[(32 * wave + 8 * j) * 64]);
            gload16(&Bt[(size_t)(n0 + r0) * K + k0 + kc], &sB[(32 * wave + 8 * j) * 64]);
        }
        __syncthreads();
#pragma unroll
        for (int ks2 = 0; ks2 < 2; ++ks2) {
            short8 af[4], bfr[4];
#pragma unroll
            for (int mt = 0; mt < 4; ++mt) {
                int Ra = 64 * wr + 16 * mt + mIdx;
                af[mt] = *(const short8*)&sA[Ra * 64 + 8 * ((ks2 * 4 + quad) ^ (Ra & 7))];
            }
#pragma unroll
            for (int nt = 0; nt < 4; ++nt) {
                int Rb = 64 * wc + 16 * nt + mIdx;
                bfr[nt] = *(const short8*)&sB[Rb * 64 + 8 * ((ks2 * 4 + quad) ^ (Rb & 7))];
            }
#pragma unroll
            for (int mt = 0; mt < 4; ++mt)
#pragma unroll
                for (int nt = 0; nt < 4; ++nt)
                    acc[mt][nt] = __builtin_amdgcn_mfma_f32_16x16x32_bf16(
                        af[mt], bfr[nt], acc[mt][nt], 0, 0, 0);
        }
        __syncthreads();
    }
    // after the final barrier every wave is done reading sA/sB -> smem reusable

    if (n0 >= 2048) {
        // ---- v region: assemble vpack tile (32 frags x 1KB) in LDS ----
        // local frag: lblk = ((hh*2+ktl)*4 + (d>>4))*2 + ((t>>5)&1), hh = wc
#pragma unroll
        for (int mt = 0; mt < 4; ++mt) {
            const int tl0 = 64 * wr + 16 * mt + 4 * quad;   // local key idx, %4==0
#pragma unroll
            for (int nt = 0; nt < 4; ++nt) {
                const int d = 16 * nt + mIdx;               // head-dim 0..63
                const int lblk = ((wc * 2 + (tl0 >> 6)) * 4 + (d >> 4)) * 2
                                 + ((tl0 >> 5) & 1);
                const int ln = (d & 15) + 16 * ((tl0 >> 3) & 3);
                uint2 pr;
                pr.x = pack_bf2(acc[mt][nt][0], acc[mt][nt][1]);
                pr.y = pack_bf2(acc[mt][nt][2], acc[mt][nt][3]);
                *(uint2*)&smem[lblk * 512 + ln * 8 + (tl0 & 7)] = pr;
            }
        }
        __syncthreads();
        {
            const int b = m0 >> 11;
            const int h0 = (n0 - 2048) >> 6;
            const int ktb = (m0 & 2047) >> 6;
#pragma unroll
            for (int g2 = 0; g2 < 4; ++g2) {                // g2 = hh*2 + ktl
                const int bh = b * 16 + h0 + (g2 >> 1);
                const int kt = ktb + (g2 & 1);
                u16* dst = vp + ((size_t)(bh * 32 + kt) * 8) * 512;
                const u16* src = &smem[g2 * 8 * 512];
#pragma unroll
                for (int ps = 0; ps < 2; ++ps) {
                    const int off = (ps * 256 + tid) * 8;
                    *(uint4*)&dst[off] = *(const uint4*)&src[off];
                }
            }
        }
    } else {
        // ---- q/k region: RMSNorm over head dim + RoPE; q prescaled log2e/8 --
        const bool isq = (n0 < 1024);
        const float* scv = isq ? qs : ks;
        const float pre = isq ? 0.18033688011112042f : 1.0f;
        float scl[4];
#pragma unroll
        for (int nt = 0; nt < 4; ++nt) scl[nt] = scv[16 * nt + mIdx];

#pragma unroll
        for (int mt = 0; mt < 4; ++mt) {
#pragma unroll
            for (int r = 0; r < 4; ++r) {
                float s = 0.f;
#pragma unroll
                for (int nt = 0; nt < 4; ++nt) {
                    float a = acc[mt][nt][r];
                    s += a * a;
                }
                s += __shfl_xor(s, 1);
                s += __shfl_xor(s, 2);
                s += __shfl_xor(s, 4);
                s += __shfl_xor(s, 8);
                float rn = rsqrtf(s * (1.f / 64.f) + 1e-6f);
                const int tl = 64 * wr + 16 * mt + 4 * quad + r;   // local token
                const int R = m0 + tl;                              // = b*L + l
                size_t peo = (size_t)R * 128;
#pragma unroll
                for (int nt = 0; nt < 4; ++nt) {
                    float v = acc[mt][nt][r] * rn * scl[nt];
                    float pp = __shfl_xor(v, 1);
                    float2 pw = *(const float2*)&pe[peo + 2 * (16 * nt + mIdx)];
                    float e  = (mIdx & 1) ? pp : v;
                    float od = (mIdx & 1) ? v : pp;
                    u16 val = f2bf((pw.x * e + pw.y * od) * pre);
                    if (isq) {
                        C[(size_t)R * N + n0 + 64 * wc + 16 * nt + mIdx] = val;
                    } else {
                        // assemble kpack tile in LDS (frag order), store later
                        const int d = 16 * nt + mIdx;
                        const int lblk = ((wc * 2 + (tl >> 6)) * 4 + ((tl >> 4) & 3)) * 2
                                         + (d >> 5);
                        smem[lblk * 512 + ((tl & 15) + 16 * ((d >> 3) & 3)) * 8
                             + (d & 7)] = val;
                    }
                }
            }
        }
        if (!isq) {
            __syncthreads();
            const int b = m0 >> 11;
            const int h0 = (n0 - 1024) >> 6;
            const int ktb = (m0 & 2047) >> 6;
#pragma unroll
            for (int g2 = 0; g2 < 4; ++g2) {                // g2 = hh*2 + ktl
                const int bh = b * 16 + h0 + (g2 >> 1);
                const int kt = ktb + (g2 & 1);
                u16* dst = kp + ((size_t)(bh * 32 + kt) * 8) * 512;
                const u16* src = &smem[g2 * 8 * 512];
#pragma unroll
                for (int ps = 0; ps < 2; ++ps) {
                    const int off = (ps * 256 + tid) * 8;
                    *(uint4*)&dst[off] = *(const uint4*)&src[off];
                }
            }
        }
    }
}

// ---------------- proj GEMM (global_load_lds staging, 64x128 tile) ------------
__global__ __launch_bounds__(256) void gemm_proj(
    const u16* __restrict__ A, const u16* __restrict__ Bt,
    const float* __restrict__ bias, float* __restrict__ C)
{
    __shared__ u16 sA[64 * 64];
    __shared__ u16 sB[128 * 64];

    const int tid = threadIdx.x;
    const int wave = tid >> 6, lane = tid & 63;
    const int mIdx = lane & 15, quad = lane >> 4;
    const int wr = wave >> 1, wc = wave & 1;   // 2x2 waves of 32x64
    const int m0 = blockIdx.y * 64, n0 = blockIdx.x * 128;
    const int N = DIMM, K = DIMM;
    const int lr = lane >> 3, lc = lane & 7;

    f32x4 acc[2][4];
#pragma unroll
    for (int a = 0; a < 2; ++a)
#pragma unroll
        for (int b = 0; b < 4; ++b) acc[a][b] = (f32x4){0.f, 0.f, 0.f, 0.f};

    for (int k0 = 0; k0 < K; k0 += 64) {
#pragma unroll
        for (int j = 0; j < 2; ++j) {       // A: 64 rows
            int r0 = 16 * wave + 8 * j + lr;
            int kc = 8 * (lc ^ (r0 & 7));
            gload16(&A[(size_t)(m0 + r0) * K + k0 + kc], &sA[(16 * wave + 8 * j) * 64]);
        }
#pragma unroll
        for (int j = 0; j < 4; ++j) {       // B: 128 rows
            int r0 = 32 * wave + 8 * j + lr;
            int kc = 8 * (lc ^ (r0 & 7));
            gload16(&Bt[(size_t)(n0 + r0) * K + k0 + kc], &sB[(32 * wave + 8 * j) * 64]);
        }
        __syncthreads();
#pragma unroll
        for (int ks2 = 0; ks2 < 2; ++ks2) {
            short8 af[2], bfr[4];
#pragma unroll
            for (int mt = 0; mt < 2; ++mt) {
                int Ra = 32 * wr + 16 * mt + mIdx;
                af[mt] = *(const short8*)&sA[Ra * 64 + 8 * ((ks2 * 4 + quad) ^ (Ra & 7))];
            }
#pragma unroll
            for (int nt = 0; nt < 4; ++nt) {
                int Rb = 64 * wc + 16 * nt + mIdx;
                bfr[nt] = *(const short8*)&sB[Rb * 64 + 8 * ((ks2 * 4 + quad) ^ (Rb & 7))];
            }
#pragma unroll
            for (int mt = 0; mt < 2; ++mt)
#pragma unroll
                for (int nt = 0; nt < 4; ++nt)
                    acc[mt][nt] = __builtin_amdgcn_mfma_f32_16x16x32_bf16(
                        af[mt], bfr[nt], acc[mt][nt], 0, 0, 0);
        }
        __syncthreads();
    }

#pragma unroll
    for (int mt = 0; mt < 2; ++mt)
#pragma unroll
        for (int r = 0; r < 4; ++r) {
            int row = m0 + 32 * wr + 16 * mt + quad * 4 + r;
#pragma unroll
            for (int nt = 0; nt < 4; ++nt) {
                int col = n0 + 64 * wc + 16 * nt + mIdx;
                C[(size_t)row * N + col] = acc[mt][nt][r] + bias[col];
            }
        }
}

// ---------------- flash attention: fragment-direct, barrier-free --------------
// R13 (kept unchanged in R14): K/V operands load straight from L1/L2-resident
// fragment-packed buffers (one coalesced dwordx4 per fragment, base+lane*16);
// LDS carries only P (same-wave, no barrier). ZERO barriers: waves free-run.
// K register-double-buffered; V loads at iter top, covered by S^T phase.
// l computed by MFMA against an all-ones fragment (no VALU adds, no shuffles).
__global__ __launch_bounds__(256, 2) void attn_mfma(
    const u16* __restrict__ qkv, const u16* __restrict__ kp,
    const u16* __restrict__ vp, u16* __restrict__ o)
{
    __shared__ u16 sP[128 * 64];

    const int tid = threadIdx.x;
    const int wave = tid >> 6;     // 0..3
    const int lane = tid & 63;
    const int mIdx = lane & 15;
    const int quad = lane >> 4;
    const int m7 = mIdx & 7;

    // XCD-chunked swizzle (512 blocks, 8 XCDs, 64 logical blocks per XCD)
    const int bid = ((blockIdx.x & 7) << 6) | (blockIdx.x >> 3);
    const int bh = bid >> 4;          // 16 q-tiles of 128 rows per (b,h)
    const int qt = bid & 15;
    const int b = bh >> 4, h = bh & 15;
    const int q0 = qt * 128;

    // fragment bases: tile kt at +kt*4096 u16; fragment f=nb*2+c at +f*512
    const u16* kbase = kp + (size_t)bh * 32 * 4096 + lane * 8;
    const u16* vbase = vp + (size_t)bh * 32 * 4096 + lane * 8;

    // Q fragments: 2 groups of 16 rows per wave
    short8 aq[2][2];
#pragma unroll
    for (int g = 0; g < 2; ++g) {
        const u16* qrow = qkv + (size_t)b * LL * QKV_N + h * 64
                          + (size_t)(q0 + 32 * wave + 16 * g + mIdx) * QKV_N;
        aq[g][0] = *(const short8*)&qrow[quad * 8];
        aq[g][1] = *(const short8*)&qrow[32 + quad * 8];
    }

    const short8 bones = {(short)0x3F80, (short)0x3F80, (short)0x3F80, (short)0x3F80,
                          (short)0x3F80, (short)0x3F80, (short)0x3F80, (short)0x3F80};

    f32x4 Oacc[2][4];
    f32x4 lac[2];
#pragma unroll
    for (int g = 0; g < 2; ++g) {
        lac[g] = (f32x4){0.f, 0.f, 0.f, 0.f};
#pragma unroll
        for (int nb = 0; nb < 4; ++nb) Oacc[g][nb] = (f32x4){0.f, 0.f, 0.f, 0.f};
    }

    // P swizzle offsets (same proven pattern as R11/R12)
    const int o0 = 8 * (quad ^ m7);
    const int o1 = 8 * ((quad + 4) ^ m7);
    u16* sPr0 = &sP[(32 * wave + mIdx) * 64];
    u16* sPr1 = &sP[(32 * wave + 16 + mIdx) * 64];

    short8 kfA[8], kfB[8], vf[8];

    // prologue: K fragments of tile 0
#pragma unroll
    for (int f = 0; f < 8; ++f) kfA[f] = *(const short8*)&kbase[f * 512];

    auto body = [&](short8* KC, short8* KN, int kt) {
        const size_t tb = (size_t)kt * 4096;
        // V fragments for THIS tile (consumed after S^T phase)
#pragma unroll
        for (int f = 0; f < 8; ++f) vf[f] = *(const short8*)&vbase[tb + f * 512];
        // K fragments for NEXT tile (consumed next body)
        if (kt < 31) {
#pragma unroll
            for (int f = 0; f < 8; ++f) KN[f] = *(const short8*)&kbase[tb + 4096 + f * 512];
        }
        __builtin_amdgcn_sched_barrier(0);

        // ---- S^T strips: D[key][q] = mfma(A=K-frag, B=Q-frag) ----
#pragma unroll
        for (int nb = 0; nb < 4; ++nb) {
            const int pofs = (16 * nb + 4 * quad) ^ (8 * m7);
#pragma unroll
            for (int g = 0; g < 2; ++g) {
                f32x4 st = (f32x4){0.f, 0.f, 0.f, 0.f};
                st = __builtin_amdgcn_mfma_f32_16x16x32_bf16(KC[nb * 2 + 0], aq[g][0], st, 0, 0, 0);
                st = __builtin_amdgcn_mfma_f32_16x16x32_bf16(KC[nb * 2 + 1], aq[g][1], st, 0, 0, 0);
                float p0 = exp2f(st[0]), p1 = exp2f(st[1]);
                float p2 = exp2f(st[2]), p3 = exp2f(st[3]);
                uint2 wp;
                wp.x = pack_bf2(p0, p1);
                wp.y = pack_bf2(p2, p3);
                *(uint2*)&((g == 0 ? sPr0 : sPr1)[pofs]) = wp;
            }
        }
        // sP rows written and read by the same wave -> no barrier.
        short8 pa00 = *(const short8*)&sPr0[o0];
        short8 pa01 = *(const short8*)&sPr0[o1];
        short8 pa10 = *(const short8*)&sPr1[o0];
        short8 pa11 = *(const short8*)&sPr1[o1];

        // l accumulation via MFMA with all-ones B (no VALU adds, no shuffles)
        lac[0] = __builtin_amdgcn_mfma_f32_16x16x32_bf16(pa00, bones, lac[0], 0, 0, 0);
        lac[0] = __builtin_amdgcn_mfma_f32_16x16x32_bf16(pa01, bones, lac[0], 0, 0, 0);
        lac[1] = __builtin_amdgcn_mfma_f32_16x16x32_bf16(pa10, bones, lac[1], 0, 0, 0);
        lac[1] = __builtin_amdgcn_mfma_f32_16x16x32_bf16(pa11, bones, lac[1], 0, 0, 0);

        // ---- O += P @ V ----
        __builtin_amdgcn_s_setprio(1);
#pragma unroll
        for (int nb = 0; nb < 4; ++nb) {
            Oacc[0][nb] = __builtin_amdgcn_mfma_f32_16x16x32_bf16(pa00, vf[nb * 2 + 0], Oacc[0][nb], 0, 0, 0);
            Oacc[0][nb] = __builtin_amdgcn_mfma_f32_16x16x32_bf16(pa01, vf[nb * 2 + 1], Oacc[0][nb], 0, 0, 0);
            Oacc[1][nb] = __builtin_amdgcn_mfma_f32_16x16x32_bf16(pa10, vf[nb * 2 + 0], Oacc[1][nb], 0, 0, 0);
            Oacc[1][nb] = __builtin_amdgcn_mfma_f32_16x16x32_bf16(pa11, vf[nb * 2 + 1], Oacc[1][nb], 0, 0, 0);
        }
        __builtin_amdgcn_s_setprio(0);
    };

    for (int kt2 = 0; kt2 < 16; ++kt2) {
        body(kfA, kfB, 2 * kt2);
        body(kfB, kfA, 2 * kt2 + 1);
    }

    // epilogue: l for q-row quad*4+r (within group g) sits in lac[g][r] of
    // EVERY lane (all-ones B makes all columns equal) — no shuffles needed.
#pragma unroll
    for (int g = 0; g < 2; ++g)
#pragma unroll
        for (int r = 0; r < 4; ++r) {
            float linv = 1.f / lac[g][r];
            const int rowg = b * LL + q0 + 32 * wave + 16 * g + quad * 4 + r;
#pragma unroll
            for (int nb = 0; nb < 4; ++nb) {
                o[(size_t)rowg * DIMM + h * 64 + 16 * nb + mIdx] =
                    f2bf(Oacc[g][nb][r] * linv);
            }
        }
}

extern "C" void kernel_launch(void* const* d_in, const int* in_sizes, int n_in,
                              void* d_out, int out_size, void* d_ws, size_t ws_size,
                              hipStream_t stream) {
    const float* x       = (const float*)d_in[0];
    const float* pe      = (const float*)d_in[1];
    const float* w_qkv   = (const float*)d_in[2];
    const float* q_scale = (const float*)d_in[3];
    const float* k_scale = (const float*)d_in[4];
    const float* w_proj  = (const float*)d_in[5];
    const float* b_proj  = (const float*)d_in[6];
    float* out = (float*)d_out;

    char* ws = (char*)d_ws;
    u16* qkv    = (u16*)ws;  ws += (size_t)4096 * 3072 * 2;
    u16* o      = (u16*)ws;  ws += (size_t)4096 * 1024 * 2;
    u16* xb     = (u16*)ws;  ws += (size_t)4096 * 1024 * 2;
    u16* wqkvt  = (u16*)ws;  ws += (size_t)3072 * 1024 * 2;
    u16* wprojt = (u16*)ws;  ws += (size_t)1024 * 1024 * 2;
    u16* kpack  = (u16*)ws;  ws += (size_t)32 * 32 * 4096 * 2;   // 8.4 MB
    u16* vpack  = (u16*)ws;  ws += (size_t)32 * 32 * 4096 * 2;   // 8.4 MB

    // 0. conversions
    convx<<<(4096 * 1024) / (256 * 8), 256, 0, stream>>>(x, xb);
    convt<<<dim3(1024 / 64, QKV_N / 64), 256, 0, stream>>>(w_qkv, wqkvt, DIMM, QKV_N);
    convt<<<dim3(1024 / 64, 1024 / 64), 256, 0, stream>>>(w_proj, wprojt, DIMM, DIMM);

    // 1. fused QKV projection + RMSNorm/RoPE (q->qkv, k->kpack) + v->vpack
    gemm_qkv<<<dim3(QKV_N / 128, (BB * LL) / 128), 256, 0, stream>>>(
        xb, wqkvt, qkv, kpack, vpack, pe, q_scale, k_scale);

    // 2. attention (fragment-direct K/V, barrier-free)
    attn_mfma<<<BB * HH * (LL / 128), 256, 0, stream>>>(qkv, kpack, vpack, o);

    // 3. output projection + bias (f32 out)
    gemm_proj<<<dim3(DIMM / 128, (BB * LL) / 64), 256, 0, stream>>>(
        o, wprojt, b_proj, out);
}

// Round 5
// 231.520 us; speedup vs baseline: 1.0379x; 1.0224x over previous
//
#include <hip/hip_runtime.h>
#include <math.h>

#define BB 2
#define LL 2048
#define DIMM 1024
#define HH 16
#define DD 64
#define QKV_N 3072

typedef unsigned short u16;
typedef unsigned int u32;
typedef __attribute__((ext_vector_type(8))) short short8;   // 8 x bf16
typedef __attribute__((ext_vector_type(4))) float f32x4;

__device__ __forceinline__ float bf2f(u16 h) {
    unsigned u = ((unsigned)h) << 16;
    return __uint_as_float(u);
}
__device__ __forceinline__ u16 f2bf(float f) {
    unsigned u = __float_as_uint(f);
    u += 0x7fffu + ((u >> 16) & 1u);   // round-to-nearest-even
    return (u16)(u >> 16);
}
// pack two f32 -> (bf16(hi)<<16)|bf16(lo), round-half-up
__device__ __forceinline__ u32 pack_bf2(float lo, float hi) {
    u32 a = __float_as_uint(hi) + 0x8000u;
    u32 b = __float_as_uint(lo) + 0x8000u;
    return __builtin_amdgcn_perm(a, b, 0x07060302u);
}
// async global->LDS, 16B per lane; LDS dst is wave-uniform base + lane*16
__device__ __forceinline__ void gload16(const u16* g, u16* l) {
    __builtin_amdgcn_global_load_lds(
        (const __attribute__((address_space(1))) void*)g,
        (__attribute__((address_space(3))) void*)l, 16, 0, 0);
}

// ---------------- f32 -> bf16 convert (x) -------------------------------------
__global__ __launch_bounds__(256) void convx(
    const float* __restrict__ X, u16* __restrict__ Xb)
{
    int i = (blockIdx.x * 256 + threadIdx.x) * 8;
    float4 a = *(const float4*)&X[i];
    float4 b = *(const float4*)&X[i + 4];
    u16 t[8] = {f2bf(a.x), f2bf(a.y), f2bf(a.z), f2bf(a.w),
                f2bf(b.x), f2bf(b.y), f2bf(b.z), f2bf(b.w)};
    *(uint4*)&Xb[i] = *(uint4*)t;
}

// ---------------- f32 [K,N] -> bf16 [N,K] transpose-convert -------------------
__global__ __launch_bounds__(256) void convt(
    const float* __restrict__ W, u16* __restrict__ Wt, int K, int N)
{
    __shared__ u16 s[64][72];
    const int tid = threadIdx.x;
    const int k0 = blockIdx.x * 64, n0 = blockIdx.y * 64;
#pragma unroll
    for (int t = 0; t < 16; ++t) {
        int flat = t * 256 + tid;
        int kk = flat >> 6, nn = flat & 63;
        s[nn][kk] = f2bf(W[(size_t)(k0 + kk) * N + n0 + nn]);
    }
    __syncthreads();
#pragma unroll
    for (int t = 0; t < 2; ++t) {
        int chunk = t * 256 + tid;
        int nn = chunk >> 3, kc = chunk & 7;
        *(uint4*)&Wt[(size_t)(n0 + nn) * K + k0 + kc * 8] = *(uint4*)&s[nn][kc * 8];
    }
}

// ---------------- QKV GEMM: 2-phase double-buffered (R15) + fused epilogues ---
// R4 post-mortem: all pipes idle (Mfma 9%, VALU 16%, HBM 9%) -> the
// single-buffered {stage; sync(vmcnt0); compute; sync} loop exposed the full
// DMA latency 16x per block. Now: STAGE(buf^1, t+1) issues BEFORE compute(buf),
// so tile t+1's DMAs fly under tile t's ds_read+MFMA phase; one
// __syncthreads()/iter does drain + visibility + WAR protection.
// XCD-chunked grid: per-XCD chunk = 8 M-blocks x 12 N-blocks (A 2MB + B 3MB
// ~ L2-resident; proven on attn in R12: FETCH 69.7->12.4 MB).
__global__ __launch_bounds__(256) void gemm_qkv(
    const u16* __restrict__ A, const u16* __restrict__ Bt,
    u16* __restrict__ C, u16* __restrict__ kp, u16* __restrict__ vp,
    const float* __restrict__ pe,
    const float* __restrict__ qs, const float* __restrict__ ks)
{
    __shared__ u16 smem[2 * 16384];   // [dbuf][sA(8K u16) | sB(8K u16)]; buf0 reused for pack

    const int tid = threadIdx.x;
    const int wave = tid >> 6, lane = tid & 63;
    const int mIdx = lane & 15, quad = lane >> 4;
    const int wr = wave >> 1, wc = wave & 1;
    // XCD-chunked swizzle: 768 blocks = 8 XCDs x 96; chunk = 8M x 12N
    const int xcd = blockIdx.x & 7, lid = blockIdx.x >> 3;
    const int m0 = ((xcd & 3) * 8 + (lid & 7)) * 128;
    const int n0 = ((xcd >> 2) * 12 + (lid >> 3)) * 128;
    const int N = QKV_N, K = DIMM;
    const int lr = lane >> 3, lc = lane & 7;

    f32x4 acc[4][4];
#pragma unroll
    for (int a = 0; a < 4; ++a)
#pragma unroll
        for (int b = 0; b < 4; ++b) acc[a][b] = (f32x4){0.f, 0.f, 0.f, 0.f};

    auto stage = [&](int buf, int k0) {
        u16* sA = smem + buf * 16384;
        u16* sB = sA + 8192;
#pragma unroll
        for (int j = 0; j < 4; ++j) {
            int r0 = 32 * wave + 8 * j + lr;
            int kc = 8 * (lc ^ lr);   // r0&7 == lr
            gload16(&A[(size_t)(m0 + r0) * K + k0 + kc], &sA[(32 * wave + 8 * j) * 64]);
            gload16(&Bt[(size_t)(n0 + r0) * K + k0 + kc], &sB[(32 * wave + 8 * j) * 64]);
        }
    };

    stage(0, 0);
    __syncthreads();
    int cur = 0;
    for (int t = 0; t < 16; ++t) {
        if (t + 1 < 16) stage(cur ^ 1, (t + 1) * 64);   // prefetch under compute
        const u16* sA = smem + cur * 16384;
        const u16* sB = sA + 8192;
#pragma unroll
        for (int ks2 = 0; ks2 < 2; ++ks2) {
            short8 af[4], bfr[4];
#pragma unroll
            for (int mt = 0; mt < 4; ++mt) {
                int Ra = 64 * wr + 16 * mt + mIdx;
                af[mt] = *(const short8*)&sA[Ra * 64 + 8 * ((ks2 * 4 + quad) ^ (Ra & 7))];
            }
#pragma unroll
            for (int nt = 0; nt < 4; ++nt) {
                int Rb = 64 * wc + 16 * nt + mIdx;
                bfr[nt] = *(const short8*)&sB[Rb * 64 + 8 * ((ks2 * 4 + quad) ^ (Rb & 7))];
            }
#pragma unroll
            for (int mt = 0; mt < 4; ++mt)
#pragma unroll
                for (int nt = 0; nt < 4; ++nt)
                    acc[mt][nt] = __builtin_amdgcn_mfma_f32_16x16x32_bf16(
                        af[mt], bfr[nt], acc[mt][nt], 0, 0, 0);
        }
        __syncthreads();   // drain DMAs + compute-read completion (WAR)
        cur ^= 1;
    }
    // after the final barrier every wave is done with LDS -> smem reusable

    if (n0 >= 2048) {
        // ---- v region: assemble vpack tile (32 frags x 1KB) in LDS ----
#pragma unroll
        for (int mt = 0; mt < 4; ++mt) {
            const int tl0 = 64 * wr + 16 * mt + 4 * quad;   // local key idx, %4==0
#pragma unroll
            for (int nt = 0; nt < 4; ++nt) {
                const int d = 16 * nt + mIdx;               // head-dim 0..63
                const int lblk = ((wc * 2 + (tl0 >> 6)) * 4 + (d >> 4)) * 2
                                 + ((tl0 >> 5) & 1);
                const int ln = (d & 15) + 16 * ((tl0 >> 3) & 3);
                uint2 pr;
                pr.x = pack_bf2(acc[mt][nt][0], acc[mt][nt][1]);
                pr.y = pack_bf2(acc[mt][nt][2], acc[mt][nt][3]);
                *(uint2*)&smem[lblk * 512 + ln * 8 + (tl0 & 7)] = pr;
            }
        }
        __syncthreads();
        {
            const int b = m0 >> 11;
            const int h0 = (n0 - 2048) >> 6;
            const int ktb = (m0 & 2047) >> 6;
#pragma unroll
            for (int g2 = 0; g2 < 4; ++g2) {                // g2 = hh*2 + ktl
                const int bh = b * 16 + h0 + (g2 >> 1);
                const int kt = ktb + (g2 & 1);
                u16* dst = vp + ((size_t)(bh * 32 + kt) * 8) * 512;
                const u16* src = &smem[g2 * 8 * 512];
#pragma unroll
                for (int ps = 0; ps < 2; ++ps) {
                    const int off = (ps * 256 + tid) * 8;
                    *(uint4*)&dst[off] = *(const uint4*)&src[off];
                }
            }
        }
    } else {
        // ---- q/k region: RMSNorm over head dim + RoPE; q prescaled log2e/8 --
        const bool isq = (n0 < 1024);
        const float* scv = isq ? qs : ks;
        const float pre = isq ? 0.18033688011112042f : 1.0f;
        float scl[4];
#pragma unroll
        for (int nt = 0; nt < 4; ++nt) scl[nt] = scv[16 * nt + mIdx];

#pragma unroll
        for (int mt = 0; mt < 4; ++mt) {
#pragma unroll
            for (int r = 0; r < 4; ++r) {
                float s = 0.f;
#pragma unroll
                for (int nt = 0; nt < 4; ++nt) {
                    float a = acc[mt][nt][r];
                    s += a * a;
                }
                s += __shfl_xor(s, 1);
                s += __shfl_xor(s, 2);
                s += __shfl_xor(s, 4);
                s += __shfl_xor(s, 8);
                float rn = rsqrtf(s * (1.f / 64.f) + 1e-6f);
                const int tl = 64 * wr + 16 * mt + 4 * quad + r;   // local token
                const int R = m0 + tl;                              // = b*L + l
                size_t peo = (size_t)R * 128;
#pragma unroll
                for (int nt = 0; nt < 4; ++nt) {
                    float v = acc[mt][nt][r] * rn * scl[nt];
                    float pp = __shfl_xor(v, 1);
                    float2 pw = *(const float2*)&pe[peo + 2 * (16 * nt + mIdx)];
                    float e  = (mIdx & 1) ? pp : v;
                    float od = (mIdx & 1) ? v : pp;
                    u16 val = f2bf((pw.x * e + pw.y * od) * pre);
                    if (isq) {
                        C[(size_t)R * N + n0 + 64 * wc + 16 * nt + mIdx] = val;
                    } else {
                        // assemble kpack tile in LDS (frag order), store later
                        const int d = 16 * nt + mIdx;
                        const int lblk = ((wc * 2 + (tl >> 6)) * 4 + ((tl >> 4) & 3)) * 2
                                         + (d >> 5);
                        smem[lblk * 512 + ((tl & 15) + 16 * ((d >> 3) & 3)) * 8
                             + (d & 7)] = val;
                    }
                }
            }
        }
        if (!isq) {
            __syncthreads();
            const int b = m0 >> 11;
            const int h0 = (n0 - 1024) >> 6;
            const int ktb = (m0 & 2047) >> 6;
#pragma unroll
            for (int g2 = 0; g2 < 4; ++g2) {                // g2 = hh*2 + ktl
                const int bh = b * 16 + h0 + (g2 >> 1);
                const int kt = ktb + (g2 & 1);
                u16* dst = kp + ((size_t)(bh * 32 + kt) * 8) * 512;
                const u16* src = &smem[g2 * 8 * 512];
#pragma unroll
                for (int ps = 0; ps < 2; ++ps) {
                    const int off = (ps * 256 + tid) * 8;
                    *(uint4*)&dst[off] = *(const uint4*)&src[off];
                }
            }
        }
    }
}

// ---------------- proj GEMM: 2-phase double-buffered (R15), 64x128 tile -------
__global__ __launch_bounds__(256) void gemm_proj(
    const u16* __restrict__ A, const u16* __restrict__ Bt,
    const float* __restrict__ bias, float* __restrict__ C)
{
    __shared__ u16 smem[2 * 12288];   // [dbuf][sA(4K u16) | sB(8K u16)] = 48KB

    const int tid = threadIdx.x;
    const int wave = tid >> 6, lane = tid & 63;
    const int mIdx = lane & 15, quad = lane >> 4;
    const int wr = wave >> 1, wc = wave & 1;   // 2x2 waves of 32x64
    // XCD-chunked swizzle: 512 blocks = 8 XCDs x 64; chunk = 8M x 8N
    const int xcd = blockIdx.x & 7, lid = blockIdx.x >> 3;
    const int m0 = (xcd * 8 + (lid >> 3)) * 64;
    const int n0 = (lid & 7) * 128;
    const int N = DIMM, K = DIMM;
    const int lr = lane >> 3, lc = lane & 7;

    f32x4 acc[2][4];
#pragma unroll
    for (int a = 0; a < 2; ++a)
#pragma unroll
        for (int b = 0; b < 4; ++b) acc[a][b] = (f32x4){0.f, 0.f, 0.f, 0.f};

    auto stage = [&](int buf, int k0) {
        u16* sA = smem + buf * 12288;
        u16* sB = sA + 4096;
#pragma unroll
        for (int j = 0; j < 2; ++j) {       // A: 64 rows
            int r0 = 16 * wave + 8 * j + lr;
            gload16(&A[(size_t)(m0 + r0) * K + k0 + 8 * (lc ^ lr)],
                    &sA[(16 * wave + 8 * j) * 64]);
        }
#pragma unroll
        for (int j = 0; j < 4; ++j) {       // B: 128 rows
            int r0 = 32 * wave + 8 * j + lr;
            gload16(&Bt[(size_t)(n0 + r0) * K + k0 + 8 * (lc ^ lr)],
                    &sB[(32 * wave + 8 * j) * 64]);
        }
    };

    stage(0, 0);
    __syncthreads();
    int cur = 0;
    for (int t = 0; t < 16; ++t) {
        if (t + 1 < 16) stage(cur ^ 1, (t + 1) * 64);
        const u16* sA = smem + cur * 12288;
        const u16* sB = sA + 4096;
#pragma unroll
        for (int ks2 = 0; ks2 < 2; ++ks2) {
            short8 af[2], bfr[4];
#pragma unroll
            for (int mt = 0; mt < 2; ++mt) {
                int Ra = 32 * wr + 16 * mt + mIdx;
                af[mt] = *(const short8*)&sA[Ra * 64 + 8 * ((ks2 * 4 + quad) ^ (Ra & 7))];
            }
#pragma unroll
            for (int nt = 0; nt < 4; ++nt) {
                int Rb = 64 * wc + 16 * nt + mIdx;
                bfr[nt] = *(const short8*)&sB[Rb * 64 + 8 * ((ks2 * 4 + quad) ^ (Rb & 7))];
            }
#pragma unroll
            for (int mt = 0; mt < 2; ++mt)
#pragma unroll
                for (int nt = 0; nt < 4; ++nt)
                    acc[mt][nt] = __builtin_amdgcn_mfma_f32_16x16x32_bf16(
                        af[mt], bfr[nt], acc[mt][nt], 0, 0, 0);
        }
        __syncthreads();
        cur ^= 1;
    }

#pragma unroll
    for (int mt = 0; mt < 2; ++mt)
#pragma unroll
        for (int r = 0; r < 4; ++r) {
            int row = m0 + 32 * wr + 16 * mt + quad * 4 + r;
#pragma unroll
            for (int nt = 0; nt < 4; ++nt) {
                int col = n0 + 64 * wc + 16 * nt + mIdx;
                C[(size_t)row * N + col] = acc[mt][nt][r] + bias[col];
            }
        }
}

// ---------------- flash attention: fragment-direct, barrier-free --------------
// R13 (unchanged): K/V operands load straight from L1/L2-resident
// fragment-packed buffers (one coalesced dwordx4 per fragment, base+lane*16);
// LDS carries only P (same-wave, no barrier). ZERO barriers: waves free-run.
// K register-double-buffered; V loads at iter top, covered by S^T phase.
// l computed by MFMA against an all-ones fragment (no VALU adds, no shuffles).
__global__ __launch_bounds__(256, 2) void attn_mfma(
    const u16* __restrict__ qkv, const u16* __restrict__ kp,
    const u16* __restrict__ vp, u16* __restrict__ o)
{
    __shared__ u16 sP[128 * 64];

    const int tid = threadIdx.x;
    const int wave = tid >> 6;     // 0..3
    const int lane = tid & 63;
    const int mIdx = lane & 15;
    const int quad = lane >> 4;
    const int m7 = mIdx & 7;

    // XCD-chunked swizzle (512 blocks, 8 XCDs, 64 logical blocks per XCD)
    const int bid = ((blockIdx.x & 7) << 6) | (blockIdx.x >> 3);
    const int bh = bid >> 4;          // 16 q-tiles of 128 rows per (b,h)
    const int qt = bid & 15;
    const int b = bh >> 4, h = bh & 15;
    const int q0 = qt * 128;

    // fragment bases: tile kt at +kt*4096 u16; fragment f=nb*2+c at +f*512
    const u16* kbase = kp + (size_t)bh * 32 * 4096 + lane * 8;
    const u16* vbase = vp + (size_t)bh * 32 * 4096 + lane * 8;

    // Q fragments: 2 groups of 16 rows per wave
    short8 aq[2][2];
#pragma unroll
    for (int g = 0; g < 2; ++g) {
        const u16* qrow = qkv + (size_t)b * LL * QKV_N + h * 64
                          + (size_t)(q0 + 32 * wave + 16 * g + mIdx) * QKV_N;
        aq[g][0] = *(const short8*)&qrow[quad * 8];
        aq[g][1] = *(const short8*)&qrow[32 + quad * 8];
    }

    const short8 bones = {(short)0x3F80, (short)0x3F80, (short)0x3F80, (short)0x3F80,
                          (short)0x3F80, (short)0x3F80, (short)0x3F80, (short)0x3F80};

    f32x4 Oacc[2][4];
    f32x4 lac[2];
#pragma unroll
    for (int g = 0; g < 2; ++g) {
        lac[g] = (f32x4){0.f, 0.f, 0.f, 0.f};
#pragma unroll
        for (int nb = 0; nb < 4; ++nb) Oacc[g][nb] = (f32x4){0.f, 0.f, 0.f, 0.f};
    }

    // P swizzle offsets (same proven pattern as R11/R12)
    const int o0 = 8 * (quad ^ m7);
    const int o1 = 8 * ((quad + 4) ^ m7);
    u16* sPr0 = &sP[(32 * wave + mIdx) * 64];
    u16* sPr1 = &sP[(32 * wave + 16 + mIdx) * 64];

    short8 kfA[8], kfB[8], vf[8];

    // prologue: K fragments of tile 0
#pragma unroll
    for (int f = 0; f < 8; ++f) kfA[f] = *(const short8*)&kbase[f * 512];

    auto body = [&](short8* KC, short8* KN, int kt) {
        const size_t tb = (size_t)kt * 4096;
        // V fragments for THIS tile (consumed after S^T phase)
#pragma unroll
        for (int f = 0; f < 8; ++f) vf[f] = *(const short8*)&vbase[tb + f * 512];
        // K fragments for NEXT tile (consumed next body)
        if (kt < 31) {
#pragma unroll
            for (int f = 0; f < 8; ++f) KN[f] = *(const short8*)&kbase[tb + 4096 + f * 512];
        }
        __builtin_amdgcn_sched_barrier(0);

        // ---- S^T strips: D[key][q] = mfma(A=K-frag, B=Q-frag) ----
#pragma unroll
        for (int nb = 0; nb < 4; ++nb) {
            const int pofs = (16 * nb + 4 * quad) ^ (8 * m7);
#pragma unroll
            for (int g = 0; g < 2; ++g) {
                f32x4 st = (f32x4){0.f, 0.f, 0.f, 0.f};
                st = __builtin_amdgcn_mfma_f32_16x16x32_bf16(KC[nb * 2 + 0], aq[g][0], st, 0, 0, 0);
                st = __builtin_amdgcn_mfma_f32_16x16x32_bf16(KC[nb * 2 + 1], aq[g][1], st, 0, 0, 0);
                float p0 = exp2f(st[0]), p1 = exp2f(st[1]);
                float p2 = exp2f(st[2]), p3 = exp2f(st[3]);
                uint2 wp;
                wp.x = pack_bf2(p0, p1);
                wp.y = pack_bf2(p2, p3);
                *(uint2*)&((g == 0 ? sPr0 : sPr1)[pofs]) = wp;
            }
        }
        // sP rows written and read by the same wave -> no barrier.
        short8 pa00 = *(const short8*)&sPr0[o0];
        short8 pa01 = *(const short8*)&sPr0[o1];
        short8 pa10 = *(const short8*)&sPr1[o0];
        short8 pa11 = *(const short8*)&sPr1[o1];

        // l accumulation via MFMA with all-ones B (no VALU adds, no shuffles)
        lac[0] = __builtin_amdgcn_mfma_f32_16x16x32_bf16(pa00, bones, lac[0], 0, 0, 0);
        lac[0] = __builtin_amdgcn_mfma_f32_16x16x32_bf16(pa01, bones, lac[0], 0, 0, 0);
        lac[1] = __builtin_amdgcn_mfma_f32_16x16x32_bf16(pa10, bones, lac[1], 0, 0, 0);
        lac[1] = __builtin_amdgcn_mfma_f32_16x16x32_bf16(pa11, bones, lac[1], 0, 0, 0);

        // ---- O += P @ V ----
        __builtin_amdgcn_s_setprio(1);
#pragma unroll
        for (int nb = 0; nb < 4; ++nb) {
            Oacc[0][nb] = __builtin_amdgcn_mfma_f32_16x16x32_bf16(pa00, vf[nb * 2 + 0], Oacc[0][nb], 0, 0, 0);
            Oacc[0][nb] = __builtin_amdgcn_mfma_f32_16x16x32_bf16(pa01, vf[nb * 2 + 1], Oacc[0][nb], 0, 0, 0);
            Oacc[1][nb] = __builtin_amdgcn_mfma_f32_16x16x32_bf16(pa10, vf[nb * 2 + 0], Oacc[1][nb], 0, 0, 0);
            Oacc[1][nb] = __builtin_amdgcn_mfma_f32_16x16x32_bf16(pa11, vf[nb * 2 + 1], Oacc[1][nb], 0, 0, 0);
        }
        __builtin_amdgcn_s_setprio(0);
    };

    for (int kt2 = 0; kt2 < 16; ++kt2) {
        body(kfA, kfB, 2 * kt2);
        body(kfB, kfA, 2 * kt2 + 1);
    }

    // epilogue: l for q-row quad*4+r (within group g) sits in lac[g][r] of
    // EVERY lane (all-ones B makes all columns equal) — no shuffles needed.
#pragma unroll
    for (int g = 0; g < 2; ++g)
#pragma unroll
        for (int r = 0; r < 4; ++r) {
            float linv = 1.f / lac[g][r];
            const int rowg = b * LL + q0 + 32 * wave + 16 * g + quad * 4 + r;
#pragma unroll
            for (int nb = 0; nb < 4; ++nb) {
                o[(size_t)rowg * DIMM + h * 64 + 16 * nb + mIdx] =
                    f2bf(Oacc[g][nb][r] * linv);
            }
        }
}

extern "C" void kernel_launch(void* const* d_in, const int* in_sizes, int n_in,
                              void* d_out, int out_size, void* d_ws, size_t ws_size,
                              hipStream_t stream) {
    const float* x       = (const float*)d_in[0];
    const float* pe      = (const float*)d_in[1];
    const float* w_qkv   = (const float*)d_in[2];
    const float* q_scale = (const float*)d_in[3];
    const float* k_scale = (const float*)d_in[4];
    const float* w_proj  = (const float*)d_in[5];
    const float* b_proj  = (const float*)d_in[6];
    float* out = (float*)d_out;

    char* ws = (char*)d_ws;
    u16* qkv    = (u16*)ws;  ws += (size_t)4096 * 3072 * 2;
    u16* o      = (u16*)ws;  ws += (size_t)4096 * 1024 * 2;
    u16* xb     = (u16*)ws;  ws += (size_t)4096 * 1024 * 2;
    u16* wqkvt  = (u16*)ws;  ws += (size_t)3072 * 1024 * 2;
    u16* wprojt = (u16*)ws;  ws += (size_t)1024 * 1024 * 2;
    u16* kpack  = (u16*)ws;  ws += (size_t)32 * 32 * 4096 * 2;   // 8.4 MB
    u16* vpack  = (u16*)ws;  ws += (size_t)32 * 32 * 4096 * 2;   // 8.4 MB

    // 0. conversions
    convx<<<(4096 * 1024) / (256 * 8), 256, 0, stream>>>(x, xb);
    convt<<<dim3(1024 / 64, QKV_N / 64), 256, 0, stream>>>(w_qkv, wqkvt, DIMM, QKV_N);
    convt<<<dim3(1024 / 64, 1024 / 64), 256, 0, stream>>>(w_proj, wprojt, DIMM, DIMM);

    // 1. fused QKV projection + RMSNorm/RoPE (q->qkv, k->kpack) + v->vpack
    gemm_qkv<<<768, 256, 0, stream>>>(
        xb, wqkvt, qkv, kpack, vpack, pe, q_scale, k_scale);

    // 2. attention (fragment-direct K/V, barrier-free)
    attn_mfma<<<BB * HH * (LL / 128), 256, 0, stream>>>(qkv, kpack, vpack, o);

    // 3. output projection + bias (f32 out)
    gemm_proj<<<512, 256, 0, stream>>>(o, wprojt, b_proj, out);
}

// Round 7
// 221.404 us; speedup vs baseline: 1.0853x; 1.0457x over previous
//
#include <hip/hip_runtime.h>
#include <math.h>

#define BB 2
#define LL 2048
#define DIMM 1024
#define HH 16
#define DD 64
#define QKV_N 3072

typedef unsigned short u16;
typedef unsigned int u32;
typedef __attribute__((ext_vector_type(8))) short short8;   // 8 x bf16
typedef __attribute__((ext_vector_type(4))) float f32x4;

__device__ __forceinline__ float bf2f(u16 h) {
    unsigned u = ((unsigned)h) << 16;
    return __uint_as_float(u);
}
__device__ __forceinline__ u16 f2bf(float f) {
    unsigned u = __float_as_uint(f);
    u += 0x7fffu + ((u >> 16) & 1u);   // round-to-nearest-even
    return (u16)(u >> 16);
}
// pack two f32 -> (bf16(hi)<<16)|bf16(lo), round-half-up
__device__ __forceinline__ u32 pack_bf2(float lo, float hi) {
    u32 a = __float_as_uint(hi) + 0x8000u;
    u32 b = __float_as_uint(lo) + 0x8000u;
    return __builtin_amdgcn_perm(a, b, 0x07060302u);
}
// async global->LDS, 16B per lane; LDS dst is wave-uniform base + lane*16
__device__ __forceinline__ void gload16(const u16* g, u16* l) {
    __builtin_amdgcn_global_load_lds(
        (const __attribute__((address_space(1))) void*)g,
        (__attribute__((address_space(3))) void*)l, 16, 0, 0);
}

// ---------------- f32 -> bf16 convert, A-FRAGMENT-packed (R16) ----------------
// Af[frag*512 + lane*8 + j] = bf16(X[R][k]):
//   frag = (rt*16 + kts)*2 + ks2 ; R = rt*16 + (lane&15)
//   k = kts*64 + ks2*32 + (lane>>4)*8 + j
// Loads: per wave 16 rows x 128B contiguous; stores: 1KB contiguous per wave.
__global__ __launch_bounds__(256) void convx(
    const float* __restrict__ X, u16* __restrict__ Af)
{
    const int g = blockIdx.x * 256 + threadIdx.x;
    const int lane = g & 63;
    const int frag = g >> 6;              // 0..8191
    const int rt = frag >> 5;             // 0..255
    const int kts = (frag >> 1) & 15;     // 0..15
    const int ks2 = frag & 1;
    const int R = rt * 16 + (lane & 15);
    const int k = kts * 64 + ks2 * 32 + ((lane >> 4) & 3) * 8;
    float4 a = *(const float4*)&X[(size_t)R * DIMM + k];
    float4 b = *(const float4*)&X[(size_t)R * DIMM + k + 4];
    u16 t[8] = {f2bf(a.x), f2bf(a.y), f2bf(a.z), f2bf(a.w),
                f2bf(b.x), f2bf(b.y), f2bf(b.z), f2bf(b.w)};
    *(uint4*)&Af[(size_t)frag * 512 + lane * 8] = *(uint4*)t;
}

// ---------------- f32 [K,N] transpose-convert; fragmode: B-fragment pack ------
// fragmode=1: Wt[frag*512 + lane*8 + j] = bf16(W[k][col]),
//   frag = (ct*(K/64)+kts)*2+ks2, ct=col>>4, lane=(col&15)+16*((k>>3)&3), j=k&7
// fragmode=0: row-major [N][K] transpose (gemm_proj path, unchanged).
__global__ __launch_bounds__(256) void convt(
    const float* __restrict__ W, u16* __restrict__ Wt, int K, int N, int fragmode)
{
    __shared__ u16 s[64][72];
    const int tid = threadIdx.x;
    const int k0 = blockIdx.x * 64, n0 = blockIdx.y * 64;
#pragma unroll
    for (int t = 0; t < 16; ++t) {
        int flat = t * 256 + tid;
        int kk = flat >> 6, nn = flat & 63;
        s[nn][kk] = f2bf(W[(size_t)(k0 + kk) * N + n0 + nn]);
    }
    __syncthreads();
    if (fragmode) {
        const int kts = k0 >> 6;
        const int kdiv = K >> 6;
#pragma unroll
        for (int t2 = 0; t2 < 2; ++t2) {
            int idx = t2 * 256 + tid;
            int fpart = idx >> 6, lane_s = idx & 63;   // 8 frags per 64x64 tile
            int ct = (n0 >> 4) + (fpart >> 1);
            int ks2 = fpart & 1;
            int nn = (fpart >> 1) * 16 + (lane_s & 15);
            int kk = ks2 * 32 + ((lane_s >> 4) & 3) * 8;
            *(uint4*)&Wt[((size_t)(ct * kdiv + kts) * 2 + ks2) * 512 + lane_s * 8]
                = *(const uint4*)&s[nn][kk];
        }
    } else {
#pragma unroll
        for (int t2 = 0; t2 < 2; ++t2) {
            int chunk = t2 * 256 + tid;
            int nn = chunk >> 3, kc = chunk & 7;
            *(uint4*)&Wt[(size_t)(n0 + nn) * K + k0 + kc * 8] = *(uint4*)&s[nn][kc * 8];
        }
    }
}

// ---------------- QKV GEMM: fragment-direct, barrier-free (R16) ---------------
// R5 post-mortem: 2-phase dbuf landed at the 2-barrier structure's ceiling
// (335 TF, all pipes <20%, occupancy 13%) — the vmcnt(0) drain in
// __syncthreads 16x/block + LDS round-trip is structural. Same cure as attn
// (R13): operands are MFMA fragments loaded DIRECTLY from L2-resident packed
// buffers (one coalesced dwordx4 per fragment, wave-uniform base + lane*16).
// Main loop: per K-32 group {8 frag loads | 16 MFMAs}, register
// double-buffered, ZERO barriers, ZERO LDS (LDS only for epilogue pack).
// Waves free-run; A-frags shared by wave pairs (wr), B-frags by (wc) -> L1 hits.
__global__ __launch_bounds__(256) void gemm_qkv(
    const u16* __restrict__ Af, const u16* __restrict__ Bf,
    u16* __restrict__ C, u16* __restrict__ kp, u16* __restrict__ vp,
    const float* __restrict__ pe,
    const float* __restrict__ qs, const float* __restrict__ ks)
{
    __shared__ u16 smem[16384];   // epilogue pack buffer only (32 KB)

    const int tid = threadIdx.x;
    const int wave = tid >> 6, lane = tid & 63;
    const int mIdx = lane & 15, quad = lane >> 4;
    const int wr = wave >> 1, wc = wave & 1;
    // XCD-chunked swizzle: 768 blocks = 8 XCDs x 96; chunk = 8M x 12N
    const int xcd = blockIdx.x & 7, lid = blockIdx.x >> 3;
    const int m0 = ((xcd & 3) * 8 + (lid & 7)) * 128;
    const int n0 = ((xcd >> 2) * 12 + (lid >> 3)) * 128;
    const int N = QKV_N;

    // frag id = (rt*16 + t)*2 + ks2 (u16 offset frag*512); rt stride = 16384 u16
    const u16* abase = Af + ((size_t)((m0 >> 4) + 4 * wr)) * 16384 + lane * 8;
    const u16* bbase = Bf + ((size_t)((n0 >> 4) + 4 * wc)) * 16384 + lane * 8;

    f32x4 acc[4][4];
#pragma unroll
    for (int a = 0; a < 4; ++a)
#pragma unroll
        for (int b = 0; b < 4; ++b) acc[a][b] = (f32x4){0.f, 0.f, 0.f, 0.f};

    short8 aA[4], bA[4], aB[4], bB[4];
    // prologue: (t=0, ks2=0) -> set A
#pragma unroll
    for (int i = 0; i < 4; ++i) {
        aA[i] = *(const short8*)&abase[(size_t)i * 16384];
        bA[i] = *(const short8*)&bbase[(size_t)i * 16384];
    }

    for (int t = 0; t < 16; ++t) {
        const size_t o1 = (size_t)t * 1024 + 512;          // (t, ks2=1)
#pragma unroll
        for (int i = 0; i < 4; ++i) {
            aB[i] = *(const short8*)&abase[(size_t)i * 16384 + o1];
            bB[i] = *(const short8*)&bbase[(size_t)i * 16384 + o1];
        }
        __builtin_amdgcn_sched_barrier(0);
        // MFMA on set A (t, ks2=0) — covers set-B load latency
#pragma unroll
        for (int mt = 0; mt < 4; ++mt)
#pragma unroll
            for (int nt = 0; nt < 4; ++nt)
                acc[mt][nt] = __builtin_amdgcn_mfma_f32_16x16x32_bf16(
                    aA[mt], bA[nt], acc[mt][nt], 0, 0, 0);
        __builtin_amdgcn_sched_barrier(0);
        if (t + 1 < 16) {
            const size_t o0 = (size_t)(t + 1) * 1024;      // (t+1, ks2=0)
#pragma unroll
            for (int i = 0; i < 4; ++i) {
                aA[i] = *(const short8*)&abase[(size_t)i * 16384 + o0];
                bA[i] = *(const short8*)&bbase[(size_t)i * 16384 + o0];
            }
        }
        __builtin_amdgcn_sched_barrier(0);
        // MFMA on set B (t, ks2=1) — covers set-A load latency
#pragma unroll
        for (int mt = 0; mt < 4; ++mt)
#pragma unroll
            for (int nt = 0; nt < 4; ++nt)
                acc[mt][nt] = __builtin_amdgcn_mfma_f32_16x16x32_bf16(
                    aB[mt], bB[nt], acc[mt][nt], 0, 0, 0);
        __builtin_amdgcn_sched_barrier(0);
    }

    if (n0 >= 2048) {
        // ---- v region: assemble vpack tile (32 frags x 1KB) in LDS ----
#pragma unroll
        for (int mt = 0; mt < 4; ++mt) {
            const int tl0 = 64 * wr + 16 * mt + 4 * quad;   // local key idx, %4==0
#pragma unroll
            for (int nt = 0; nt < 4; ++nt) {
                const int d = 16 * nt + mIdx;               // head-dim 0..63
                const int lblk = ((wc * 2 + (tl0 >> 6)) * 4 + (d >> 4)) * 2
                                 + ((tl0 >> 5) & 1);
                const int ln = (d & 15) + 16 * ((tl0 >> 3) & 3);
                uint2 pr;
                pr.x = pack_bf2(acc[mt][nt][0], acc[mt][nt][1]);
                pr.y = pack_bf2(acc[mt][nt][2], acc[mt][nt][3]);
                *(uint2*)&smem[lblk * 512 + ln * 8 + (tl0 & 7)] = pr;
            }
        }
        __syncthreads();
        {
            const int b = m0 >> 11;
            const int h0 = (n0 - 2048) >> 6;
            const int ktb = (m0 & 2047) >> 6;
#pragma unroll
            for (int g2 = 0; g2 < 4; ++g2) {                // g2 = hh*2 + ktl
                const int bh = b * 16 + h0 + (g2 >> 1);
                const int kt = ktb + (g2 & 1);
                u16* dst = vp + ((size_t)(bh * 32 + kt) * 8) * 512;
                const u16* src = &smem[g2 * 8 * 512];
#pragma unroll
                for (int ps = 0; ps < 2; ++ps) {
                    const int off = (ps * 256 + tid) * 8;
                    *(uint4*)&dst[off] = *(const uint4*)&src[off];
                }
            }
        }
    } else {
        // ---- q/k region: RMSNorm over head dim + RoPE; q prescaled log2e/8 --
        const bool isq = (n0 < 1024);
        const float* scv = isq ? qs : ks;
        const float pre = isq ? 0.18033688011112042f : 1.0f;
        float scl[4];
#pragma unroll
        for (int nt = 0; nt < 4; ++nt) scl[nt] = scv[16 * nt + mIdx];

#pragma unroll
        for (int mt = 0; mt < 4; ++mt) {
#pragma unroll
            for (int r = 0; r < 4; ++r) {
                float s = 0.f;
#pragma unroll
                for (int nt = 0; nt < 4; ++nt) {
                    float a = acc[mt][nt][r];
                    s += a * a;
                }
                s += __shfl_xor(s, 1);
                s += __shfl_xor(s, 2);
                s += __shfl_xor(s, 4);
                s += __shfl_xor(s, 8);
                float rn = rsqrtf(s * (1.f / 64.f) + 1e-6f);
                const int tl = 64 * wr + 16 * mt + 4 * quad + r;   // local token
                const int R = m0 + tl;                              // = b*L + l
                size_t peo = (size_t)R * 128;
#pragma unroll
                for (int nt = 0; nt < 4; ++nt) {
                    float v = acc[mt][nt][r] * rn * scl[nt];
                    float pp = __shfl_xor(v, 1);
                    float2 pw = *(const float2*)&pe[peo + 2 * (16 * nt + mIdx)];
                    float e  = (mIdx & 1) ? pp : v;
                    float od = (mIdx & 1) ? v : pp;
                    u16 val = f2bf((pw.x * e + pw.y * od) * pre);
                    if (isq) {
                        C[(size_t)R * N + n0 + 64 * wc + 16 * nt + mIdx] = val;
                    } else {
                        // assemble kpack tile in LDS (frag order), store later
                        const int d = 16 * nt + mIdx;
                        const int lblk = ((wc * 2 + (tl >> 6)) * 4 + ((tl >> 4) & 3)) * 2
                                         + (d >> 5);
                        smem[lblk * 512 + ((tl & 15) + 16 * ((d >> 3) & 3)) * 8
                             + (d & 7)] = val;
                    }
                }
            }
        }
        if (!isq) {
            __syncthreads();
            const int b = m0 >> 11;
            const int h0 = (n0 - 1024) >> 6;
            const int ktb = (m0 & 2047) >> 6;
#pragma unroll
            for (int g2 = 0; g2 < 4; ++g2) {                // g2 = hh*2 + ktl
                const int bh = b * 16 + h0 + (g2 >> 1);
                const int kt = ktb + (g2 & 1);
                u16* dst = kp + ((size_t)(bh * 32 + kt) * 8) * 512;
                const u16* src = &smem[g2 * 8 * 512];
#pragma unroll
                for (int ps = 0; ps < 2; ++ps) {
                    const int off = (ps * 256 + tid) * 8;
                    *(uint4*)&dst[off] = *(const uint4*)&src[off];
                }
            }
        }
    }
}

// ---------------- proj GEMM: 2-phase double-buffered (R15), 64x128 tile -------
__global__ __launch_bounds__(256) void gemm_proj(
    const u16* __restrict__ A, const u16* __restrict__ Bt,
    const float* __restrict__ bias, float* __restrict__ C)
{
    __shared__ u16 smem[2 * 12288];   // [dbuf][sA(4K u16) | sB(8K u16)] = 48KB

    const int tid = threadIdx.x;
    const int wave = tid >> 6, lane = tid & 63;
    const int mIdx = lane & 15, quad = lane >> 4;
    const int wr = wave >> 1, wc = wave & 1;   // 2x2 waves of 32x64
    // XCD-chunked swizzle: 512 blocks = 8 XCDs x 64; chunk = 8M x 8N
    const int xcd = blockIdx.x & 7, lid = blockIdx.x >> 3;
    const int m0 = (xcd * 8 + (lid >> 3)) * 64;
    const int n0 = (lid & 7) * 128;
    const int N = DIMM, K = DIMM;
    const int lr = lane >> 3, lc = lane & 7;

    f32x4 acc[2][4];
#pragma unroll
    for (int a = 0; a < 2; ++a)
#pragma unroll
        for (int b = 0; b < 4; ++b) acc[a][b] = (f32x4){0.f, 0.f, 0.f, 0.f};

    auto stage = [&](int buf, int k0) {
        u16* sA = smem + buf * 12288;
        u16* sB = sA + 4096;
#pragma unroll
        for (int j = 0; j < 2; ++j) {       // A: 64 rows
            int r0 = 16 * wave + 8 * j + lr;
            gload16(&A[(size_t)(m0 + r0) * K + k0 + 8 * (lc ^ lr)],
                    &sA[(16 * wave + 8 * j) * 64]);
        }
#pragma unroll
        for (int j = 0; j < 4; ++j) {       // B: 128 rows
            int r0 = 32 * wave + 8 * j + lr;
            gload16(&Bt[(size_t)(n0 + r0) * K + k0 + 8 * (lc ^ lr)],
                    &sB[(32 * wave + 8 * j) * 64]);
        }
    };

    stage(0, 0);
    __syncthreads();
    int cur = 0;
    for (int t = 0; t < 16; ++t) {
        if (t + 1 < 16) stage(cur ^ 1, (t + 1) * 64);
        const u16* sA = smem + cur * 12288;
        const u16* sB = sA + 4096;
#pragma unroll
        for (int ks2 = 0; ks2 < 2; ++ks2) {
            short8 af[2], bfr[4];
#pragma unroll
            for (int mt = 0; mt < 2; ++mt) {
                int Ra = 32 * wr + 16 * mt + mIdx;
                af[mt] = *(const short8*)&sA[Ra * 64 + 8 * ((ks2 * 4 + quad) ^ (Ra & 7))];
            }
#pragma unroll
            for (int nt = 0; nt < 4; ++nt) {
                int Rb = 64 * wc + 16 * nt + mIdx;
                bfr[nt] = *(const short8*)&sB[Rb * 64 + 8 * ((ks2 * 4 + quad) ^ (Rb & 7))];
            }
#pragma unroll
            for (int mt = 0; mt < 2; ++mt)
#pragma unroll
                for (int nt = 0; nt < 4; ++nt)
                    acc[mt][nt] = __builtin_amdgcn_mfma_f32_16x16x32_bf16(
                        af[mt], bfr[nt], acc[mt][nt], 0, 0, 0);
        }
        __syncthreads();
        cur ^= 1;
    }

#pragma unroll
    for (int mt = 0; mt < 2; ++mt)
#pragma unroll
        for (int r = 0; r < 4; ++r) {
            int row = m0 + 32 * wr + 16 * mt + quad * 4 + r;
#pragma unroll
            for (int nt = 0; nt < 4; ++nt) {
                int col = n0 + 64 * wc + 16 * nt + mIdx;
                C[(size_t)row * N + col] = acc[mt][nt][r] + bias[col];
            }
        }
}

// ---------------- flash attention: fragment-direct, barrier-free --------------
// R13 (unchanged): K/V operands load straight from L1/L2-resident
// fragment-packed buffers (one coalesced dwordx4 per fragment, base+lane*16);
// LDS carries only P (same-wave, no barrier). ZERO barriers: waves free-run.
// K register-double-buffered; V loads at iter top, covered by S^T phase.
// l computed by MFMA against an all-ones fragment (no VALU adds, no shuffles).
__global__ __launch_bounds__(256, 2) void attn_mfma(
    const u16* __restrict__ qkv, const u16* __restrict__ kp,
    const u16* __restrict__ vp, u16* __restrict__ o)
{
    __shared__ u16 sP[128 * 64];

    const int tid = threadIdx.x;
    const int wave = tid >> 6;     // 0..3
    const int lane = tid & 63;
    const int mIdx = lane & 15;
    const int quad = lane >> 4;
    const int m7 = mIdx & 7;

    // XCD-chunked swizzle (512 blocks, 8 XCDs, 64 logical blocks per XCD)
    const int bid = ((blockIdx.x & 7) << 6) | (blockIdx.x >> 3);
    const int bh = bid >> 4;          // 16 q-tiles of 128 rows per (b,h)
    const int qt = bid & 15;
    const int b = bh >> 4, h = bh & 15;
    const int q0 = qt * 128;

    // fragment bases: tile kt at +kt*4096 u16; fragment f=nb*2+c at +f*512
    const u16* kbase = kp + (size_t)bh * 32 * 4096 + lane * 8;
    const u16* vbase = vp + (size_t)bh * 32 * 4096 + lane * 8;

    // Q fragments: 2 groups of 16 rows per wave
    short8 aq[2][2];
#pragma unroll
    for (int g = 0; g < 2; ++g) {
        const u16* qrow = qkv + (size_t)b * LL * QKV_N + h * 64
                          + (size_t)(q0 + 32 * wave + 16 * g + mIdx) * QKV_N;
        aq[g][0] = *(const short8*)&qrow[quad * 8];
        aq[g][1] = *(const short8*)&qrow[32 + quad * 8];
    }

    const short8 bones = {(short)0x3F80, (short)0x3F80, (short)0x3F80, (short)0x3F80,
                          (short)0x3F80, (short)0x3F80, (short)0x3F80, (short)0x3F80};

    f32x4 Oacc[2][4];
    f32x4 lac[2];
#pragma unroll
    for (int g = 0; g < 2; ++g) {
        lac[g] = (f32x4){0.f, 0.f, 0.f, 0.f};
#pragma unroll
        for (int nb = 0; nb < 4; ++nb) Oacc[g][nb] = (f32x4){0.f, 0.f, 0.f, 0.f};
    }

    // P swizzle offsets (same proven pattern as R11/R12)
    const int o0 = 8 * (quad ^ m7);
    const int o1 = 8 * ((quad + 4) ^ m7);
    u16* sPr0 = &sP[(32 * wave + mIdx) * 64];
    u16* sPr1 = &sP[(32 * wave + 16 + mIdx) * 64];

    short8 kfA[8], kfB[8], vf[8];

    // prologue: K fragments of tile 0
#pragma unroll
    for (int f = 0; f < 8; ++f) kfA[f] = *(const short8*)&kbase[f * 512];

    auto body = [&](short8* KC, short8* KN, int kt) {
        const size_t tb = (size_t)kt * 4096;
        // V fragments for THIS tile (consumed after S^T phase)
#pragma unroll
        for (int f = 0; f < 8; ++f) vf[f] = *(const short8*)&vbase[tb + f * 512];
        // K fragments for NEXT tile (consumed next body)
        if (kt < 31) {
#pragma unroll
            for (int f = 0; f < 8; ++f) KN[f] = *(const short8*)&kbase[tb + 4096 + f * 512];
        }
        __builtin_amdgcn_sched_barrier(0);

        // ---- S^T strips: D[key][q] = mfma(A=K-frag, B=Q-frag) ----
#pragma unroll
        for (int nb = 0; nb < 4; ++nb) {
            const int pofs = (16 * nb + 4 * quad) ^ (8 * m7);
#pragma unroll
            for (int g = 0; g < 2; ++g) {
                f32x4 st = (f32x4){0.f, 0.f, 0.f, 0.f};
                st = __builtin_amdgcn_mfma_f32_16x16x32_bf16(KC[nb * 2 + 0], aq[g][0], st, 0, 0, 0);
                st = __builtin_amdgcn_mfma_f32_16x16x32_bf16(KC[nb * 2 + 1], aq[g][1], st, 0, 0, 0);
                float p0 = exp2f(st[0]), p1 = exp2f(st[1]);
                float p2 = exp2f(st[2]), p3 = exp2f(st[3]);
                uint2 wp;
                wp.x = pack_bf2(p0, p1);
                wp.y = pack_bf2(p2, p3);
                *(uint2*)&((g == 0 ? sPr0 : sPr1)[pofs]) = wp;
            }
        }
        // sP rows written and read by the same wave -> no barrier.
        short8 pa00 = *(const short8*)&sPr0[o0];
        short8 pa01 = *(const short8*)&sPr0[o1];
        short8 pa10 = *(const short8*)&sPr1[o0];
        short8 pa11 = *(const short8*)&sPr1[o1];

        // l accumulation via MFMA with all-ones B (no VALU adds, no shuffles)
        lac[0] = __builtin_amdgcn_mfma_f32_16x16x32_bf16(pa00, bones, lac[0], 0, 0, 0);
        lac[0] = __builtin_amdgcn_mfma_f32_16x16x32_bf16(pa01, bones, lac[0], 0, 0, 0);
        lac[1] = __builtin_amdgcn_mfma_f32_16x16x32_bf16(pa10, bones, lac[1], 0, 0, 0);
        lac[1] = __builtin_amdgcn_mfma_f32_16x16x32_bf16(pa11, bones, lac[1], 0, 0, 0);

        // ---- O += P @ V ----
        __builtin_amdgcn_s_setprio(1);
#pragma unroll
        for (int nb = 0; nb < 4; ++nb) {
            Oacc[0][nb] = __builtin_amdgcn_mfma_f32_16x16x32_bf16(pa00, vf[nb * 2 + 0], Oacc[0][nb], 0, 0, 0);
            Oacc[0][nb] = __builtin_amdgcn_mfma_f32_16x16x32_bf16(pa01, vf[nb * 2 + 1], Oacc[0][nb], 0, 0, 0);
            Oacc[1][nb] = __builtin_amdgcn_mfma_f32_16x16x32_bf16(pa10, vf[nb * 2 + 0], Oacc[1][nb], 0, 0, 0);
            Oacc[1][nb] = __builtin_amdgcn_mfma_f32_16x16x32_bf16(pa11, vf[nb * 2 + 1], Oacc[1][nb], 0, 0, 0);
        }
        __builtin_amdgcn_s_setprio(0);
    };

    for (int kt2 = 0; kt2 < 16; ++kt2) {
        body(kfA, kfB, 2 * kt2);
        body(kfB, kfA, 2 * kt2 + 1);
    }

    // epilogue: l for q-row quad*4+r (within group g) sits in lac[g][r] of
    // EVERY lane (all-ones B makes all columns equal) — no shuffles needed.
#pragma unroll
    for (int g = 0; g < 2; ++g)
#pragma unroll
        for (int r = 0; r < 4; ++r) {
            float linv = 1.f / lac[g][r];
            const int rowg = b * LL + q0 + 32 * wave + 16 * g + quad * 4 + r;
#pragma unroll
            for (int nb = 0; nb < 4; ++nb) {
                o[(size_t)rowg * DIMM + h * 64 + 16 * nb + mIdx] =
                    f2bf(Oacc[g][nb][r] * linv);
            }
        }
}

extern "C" void kernel_launch(void* const* d_in, const int* in_sizes, int n_in,
                              void* d_out, int out_size, void* d_ws, size_t ws_size,
                              hipStream_t stream) {
    const float* x       = (const float*)d_in[0];
    const float* pe      = (const float*)d_in[1];
    const float* w_qkv   = (const float*)d_in[2];
    const float* q_scale = (const float*)d_in[3];
    const float* k_scale = (const float*)d_in[4];
    const float* w_proj  = (const float*)d_in[5];
    const float* b_proj  = (const float*)d_in[6];
    float* out = (float*)d_out;

    char* ws = (char*)d_ws;
    u16* qkv    = (u16*)ws;  ws += (size_t)4096 * 3072 * 2;
    u16* o      = (u16*)ws;  ws += (size_t)4096 * 1024 * 2;
    u16* xb     = (u16*)ws;  ws += (size_t)4096 * 1024 * 2;   // A-fragment-packed
    u16* wqkvt  = (u16*)ws;  ws += (size_t)3072 * 1024 * 2;   // B-fragment-packed
    u16* wprojt = (u16*)ws;  ws += (size_t)1024 * 1024 * 2;   // row-major [N][K]
    u16* kpack  = (u16*)ws;  ws += (size_t)32 * 32 * 4096 * 2;   // 8.4 MB
    u16* vpack  = (u16*)ws;  ws += (size_t)32 * 32 * 4096 * 2;   // 8.4 MB

    // 0. conversions (x and w_qkv now emit MFMA-fragment-packed layouts)
    convx<<<(4096 * 1024) / (256 * 8), 256, 0, stream>>>(x, xb);
    convt<<<dim3(1024 / 64, QKV_N / 64), 256, 0, stream>>>(w_qkv, wqkvt, DIMM, QKV_N, 1);
    convt<<<dim3(1024 / 64, 1024 / 64), 256, 0, stream>>>(w_proj, wprojt, DIMM, DIMM, 0);

    // 1. fused QKV projection (fragment-direct, barrier-free)
    //    + RMSNorm/RoPE (q->qkv, k->kpack) + v->vpack
    gemm_qkv<<<768, 256, 0, stream>>>(
        xb, wqkvt, qkv, kpack, vpack, pe, q_scale, k_scale);

    // 2. attention (fragment-direct K/V, barrier-free)
    attn_mfma<<<BB * HH * (LL / 128), 256, 0, stream>>>(qkv, kpack, vpack, o);

    // 3. output projection + bias (f32 out)
    gemm_proj<<<512, 256, 0, stream>>>(o, wprojt, b_proj, out);
}

// Round 8
// 209.454 us; speedup vs baseline: 1.1473x; 1.0571x over previous
//
#include <hip/hip_runtime.h>
#include <math.h>

#define BB 2
#define LL 2048
#define DIMM 1024
#define HH 16
#define DD 64
#define QKV_N 3072

typedef unsigned short u16;
typedef unsigned int u32;
typedef __attribute__((ext_vector_type(8))) short short8;   // 8 x bf16
typedef __attribute__((ext_vector_type(4))) float f32x4;

__device__ __forceinline__ float bf2f(u16 h) {
    unsigned u = ((unsigned)h) << 16;
    return __uint_as_float(u);
}
__device__ __forceinline__ u16 f2bf(float f) {
    unsigned u = __float_as_uint(f);
    u += 0x7fffu + ((u >> 16) & 1u);   // round-to-nearest-even
    return (u16)(u >> 16);
}
// pack two f32 -> (bf16(hi)<<16)|bf16(lo), round-half-up
__device__ __forceinline__ u32 pack_bf2(float lo, float hi) {
    u32 a = __float_as_uint(hi) + 0x8000u;
    u32 b = __float_as_uint(lo) + 0x8000u;
    return __builtin_amdgcn_perm(a, b, 0x07060302u);
}
// async global->LDS, 16B per lane; LDS dst is wave-uniform base + lane*16
__device__ __forceinline__ void gload16(const u16* g, u16* l) {
    __builtin_amdgcn_global_load_lds(
        (const __attribute__((address_space(1))) void*)g,
        (__attribute__((address_space(3))) void*)l, 16, 0, 0);
}

// ---------------- f32 -> bf16 convert, A-FRAGMENT-packed ----------------------
__global__ __launch_bounds__(256) void convx(
    const float* __restrict__ X, u16* __restrict__ Af)
{
    const int g = blockIdx.x * 256 + threadIdx.x;
    const int lane = g & 63;
    const int frag = g >> 6;              // 0..8191
    const int rt = frag >> 5;             // 0..255
    const int kts = (frag >> 1) & 15;     // 0..15
    const int ks2 = frag & 1;
    const int R = rt * 16 + (lane & 15);
    const int k = kts * 64 + ks2 * 32 + ((lane >> 4) & 3) * 8;
    float4 a = *(const float4*)&X[(size_t)R * DIMM + k];
    float4 b = *(const float4*)&X[(size_t)R * DIMM + k + 4];
    u16 t[8] = {f2bf(a.x), f2bf(a.y), f2bf(a.z), f2bf(a.w),
                f2bf(b.x), f2bf(b.y), f2bf(b.z), f2bf(b.w)};
    *(uint4*)&Af[(size_t)frag * 512 + lane * 8] = *(uint4*)t;
}

// ---------------- f32 [K,N] transpose-convert; fragmode: B-fragment pack ------
__global__ __launch_bounds__(256) void convt(
    const float* __restrict__ W, u16* __restrict__ Wt, int K, int N, int fragmode)
{
    __shared__ u16 s[64][72];
    const int tid = threadIdx.x;
    const int k0 = blockIdx.x * 64, n0 = blockIdx.y * 64;
#pragma unroll
    for (int t = 0; t < 16; ++t) {
        int flat = t * 256 + tid;
        int kk = flat >> 6, nn = flat & 63;
        s[nn][kk] = f2bf(W[(size_t)(k0 + kk) * N + n0 + nn]);
    }
    __syncthreads();
    if (fragmode) {
        const int kts = k0 >> 6;
        const int kdiv = K >> 6;
#pragma unroll
        for (int t2 = 0; t2 < 2; ++t2) {
            int idx = t2 * 256 + tid;
            int fpart = idx >> 6, lane_s = idx & 63;   // 8 frags per 64x64 tile
            int ct = (n0 >> 4) + (fpart >> 1);
            int ks2 = fpart & 1;
            int nn = (fpart >> 1) * 16 + (lane_s & 15);
            int kk = ks2 * 32 + ((lane_s >> 4) & 3) * 8;
            *(uint4*)&Wt[((size_t)(ct * kdiv + kts) * 2 + ks2) * 512 + lane_s * 8]
                = *(const uint4*)&s[nn][kk];
        }
    } else {
#pragma unroll
        for (int t2 = 0; t2 < 2; ++t2) {
            int chunk = t2 * 256 + tid;
            int nn = chunk >> 3, kc = chunk & 7;
            *(uint4*)&Wt[(size_t)(n0 + nn) * K + k0 + kc * 8] = *(uint4*)&s[nn][kc * 8];
        }
    }
}

// ---------------- QKV GEMM: split per region (R8 ablation) --------------------
// R7 post-mortem: 3 different main loops all ~75us with every pipe idle and
// occupancy 14% vs structural 37% -> whole-GPU load imbalance: the n-major
// XCD chunking put all of q+half of k (heavy RMSNorm/RoPE/scalar-store
// epilogues) on XCDs 0-3 and the cheap v region on XCDs 4-7, which idled.
// Fix + ablation: one kernel PER REGION (each spread over all 8 XCDs, and
// rocprof now reports per-region durations). q epilogue also moves to the
// proven LDS-assemble + coalesced-uint4-store pattern (64 scalar stores -> 8).
// Main loop identical to R7: fragment-direct, barrier-free, reg-dbuf.
template<int REGION>   // 0=q, 1=k, 2=v
__global__ __launch_bounds__(256) void gemm_qkv_r(
    const u16* __restrict__ Af, const u16* __restrict__ Bf,
    u16* __restrict__ C, u16* __restrict__ kp, u16* __restrict__ vp,
    const float* __restrict__ pe,
    const float* __restrict__ qs, const float* __restrict__ ks)
{
    __shared__ u16 smem[REGION == 0 ? 128 * 136 : 16384];

    const int tid = threadIdx.x;
    const int wave = tid >> 6, lane = tid & 63;
    const int mIdx = lane & 15, quad = lane >> 4;
    const int wr = wave >> 1, wc = wave & 1;
    // 256 blocks = 8 XCDs x 32; per-XCD chunk: 4 m-blocks x 8 n-blocks
    // (A-panel 1MB + B-panel 2MB -> L2-resident)
    const int xcd = blockIdx.x & 7, lid = blockIdx.x >> 3;
    const int m0 = (xcd * 4 + (lid >> 3)) * 128;
    const int nblk = lid & 7;
    const int n0 = REGION * 1024 + nblk * 128;
    const int N = QKV_N;

    // frag id = (rt*16 + t)*2 + ks2 (u16 offset frag*512); rt stride = 16384 u16
    const u16* abase = Af + ((size_t)((m0 >> 4) + 4 * wr)) * 16384 + lane * 8;
    const u16* bbase = Bf + ((size_t)((n0 >> 4) + 4 * wc)) * 16384 + lane * 8;

    f32x4 acc[4][4];
#pragma unroll
    for (int a = 0; a < 4; ++a)
#pragma unroll
        for (int b = 0; b < 4; ++b) acc[a][b] = (f32x4){0.f, 0.f, 0.f, 0.f};

    short8 aA[4], bA[4], aB[4], bB[4];
    // prologue: (t=0, ks2=0) -> set A
#pragma unroll
    for (int i = 0; i < 4; ++i) {
        aA[i] = *(const short8*)&abase[(size_t)i * 16384];
        bA[i] = *(const short8*)&bbase[(size_t)i * 16384];
    }

    for (int t = 0; t < 16; ++t) {
        const size_t o1 = (size_t)t * 1024 + 512;          // (t, ks2=1)
#pragma unroll
        for (int i = 0; i < 4; ++i) {
            aB[i] = *(const short8*)&abase[(size_t)i * 16384 + o1];
            bB[i] = *(const short8*)&bbase[(size_t)i * 16384 + o1];
        }
        __builtin_amdgcn_sched_barrier(0);
        // MFMA on set A (t, ks2=0) — covers set-B load latency
#pragma unroll
        for (int mt = 0; mt < 4; ++mt)
#pragma unroll
            for (int nt = 0; nt < 4; ++nt)
                acc[mt][nt] = __builtin_amdgcn_mfma_f32_16x16x32_bf16(
                    aA[mt], bA[nt], acc[mt][nt], 0, 0, 0);
        __builtin_amdgcn_sched_barrier(0);
        if (t + 1 < 16) {
            const size_t o0 = (size_t)(t + 1) * 1024;      // (t+1, ks2=0)
#pragma unroll
            for (int i = 0; i < 4; ++i) {
                aA[i] = *(const short8*)&abase[(size_t)i * 16384 + o0];
                bA[i] = *(const short8*)&bbase[(size_t)i * 16384 + o0];
            }
        }
        __builtin_amdgcn_sched_barrier(0);
        // MFMA on set B (t, ks2=1) — covers set-A load latency
#pragma unroll
        for (int mt = 0; mt < 4; ++mt)
#pragma unroll
            for (int nt = 0; nt < 4; ++nt)
                acc[mt][nt] = __builtin_amdgcn_mfma_f32_16x16x32_bf16(
                    aB[mt], bB[nt], acc[mt][nt], 0, 0, 0);
        __builtin_amdgcn_sched_barrier(0);
    }

    if constexpr (REGION == 2) {
        // ---- v: assemble vpack tile (32 frags x 1KB) in LDS, store coalesced -
#pragma unroll
        for (int mt = 0; mt < 4; ++mt) {
            const int tl0 = 64 * wr + 16 * mt + 4 * quad;   // local key idx, %4==0
#pragma unroll
            for (int nt = 0; nt < 4; ++nt) {
                const int d = 16 * nt + mIdx;               // head-dim 0..63
                const int lblk = ((wc * 2 + (tl0 >> 6)) * 4 + (d >> 4)) * 2
                                 + ((tl0 >> 5) & 1);
                const int ln = (d & 15) + 16 * ((tl0 >> 3) & 3);
                uint2 pr;
                pr.x = pack_bf2(acc[mt][nt][0], acc[mt][nt][1]);
                pr.y = pack_bf2(acc[mt][nt][2], acc[mt][nt][3]);
                *(uint2*)&smem[lblk * 512 + ln * 8 + (tl0 & 7)] = pr;
            }
        }
        __syncthreads();
        {
            const int b = m0 >> 11;
            const int h0 = nblk * 2;
            const int ktb = (m0 & 2047) >> 6;
#pragma unroll
            for (int g2 = 0; g2 < 4; ++g2) {                // g2 = hh*2 + ktl
                const int bh = b * 16 + h0 + (g2 >> 1);
                const int kt = ktb + (g2 & 1);
                u16* dst = vp + ((size_t)(bh * 32 + kt) * 8) * 512;
                const u16* src = &smem[g2 * 8 * 512];
#pragma unroll
                for (int ps = 0; ps < 2; ++ps) {
                    const int off = (ps * 256 + tid) * 8;
                    *(uint4*)&dst[off] = *(const uint4*)&src[off];
                }
            }
        }
    } else {
        // ---- q/k: RMSNorm over head dim + RoPE; q prescaled log2e/8 ----------
        const float* scv = (REGION == 0) ? qs : ks;
        const float pre = (REGION == 0) ? 0.18033688011112042f : 1.0f;
        float scl[4];
#pragma unroll
        for (int nt = 0; nt < 4; ++nt) scl[nt] = scv[16 * nt + mIdx];

#pragma unroll
        for (int mt = 0; mt < 4; ++mt) {
#pragma unroll
            for (int r = 0; r < 4; ++r) {
                float s = 0.f;
#pragma unroll
                for (int nt = 0; nt < 4; ++nt) {
                    float a = acc[mt][nt][r];
                    s += a * a;
                }
                s += __shfl_xor(s, 1);
                s += __shfl_xor(s, 2);
                s += __shfl_xor(s, 4);
                s += __shfl_xor(s, 8);
                float rn = rsqrtf(s * (1.f / 64.f) + 1e-6f);
                const int tl = 64 * wr + 16 * mt + 4 * quad + r;   // local token
                const int R = m0 + tl;                              // = b*L + l
                size_t peo = (size_t)R * 128;
#pragma unroll
                for (int nt = 0; nt < 4; ++nt) {
                    float v = acc[mt][nt][r] * rn * scl[nt];
                    float pp = __shfl_xor(v, 1);
                    float2 pw = *(const float2*)&pe[peo + 2 * (16 * nt + mIdx)];
                    float e  = (mIdx & 1) ? pp : v;
                    float od = (mIdx & 1) ? v : pp;
                    u16 val = f2bf((pw.x * e + pw.y * od) * pre);
                    if constexpr (REGION == 0) {
                        // assemble q tile [128][136] in LDS, store coalesced
                        smem[tl * 136 + 64 * wc + 16 * nt + mIdx] = val;
                    } else {
                        // assemble kpack tile in LDS (frag order), store later
                        const int d = 16 * nt + mIdx;
                        const int lblk = ((wc * 2 + (tl >> 6)) * 4 + ((tl >> 4) & 3)) * 2
                                         + (d >> 5);
                        smem[lblk * 512 + ((tl & 15) + 16 * ((d >> 3) & 3)) * 8
                             + (d & 7)] = val;
                    }
                }
            }
        }
        __syncthreads();
        if constexpr (REGION == 0) {
            // coalesced q store: 8 x uint4 per thread (was 64 scalar u16)
            const int row = tid >> 1, half = tid & 1;
            u16* dst = C + (size_t)(m0 + row) * QKV_N + n0 + half * 64;
            const u16* src = &smem[row * 136 + half * 64];
#pragma unroll
            for (int c = 0; c < 8; ++c)
                *(uint4*)&dst[c * 8] = *(const uint4*)&src[c * 8];
        } else {
            const int b = m0 >> 11;
            const int h0 = nblk * 2;
            const int ktb = (m0 & 2047) >> 6;
#pragma unroll
            for (int g2 = 0; g2 < 4; ++g2) {                // g2 = hh*2 + ktl
                const int bh = b * 16 + h0 + (g2 >> 1);
                const int kt = ktb + (g2 & 1);
                u16* dst = kp + ((size_t)(bh * 32 + kt) * 8) * 512;
                const u16* src = &smem[g2 * 8 * 512];
#pragma unroll
                for (int ps = 0; ps < 2; ++ps) {
                    const int off = (ps * 256 + tid) * 8;
                    *(uint4*)&dst[off] = *(const uint4*)&src[off];
                }
            }
        }
    }
}

// ---------------- proj GEMM: 2-phase double-buffered, 64x128 tile -------------
__global__ __launch_bounds__(256) void gemm_proj(
    const u16* __restrict__ A, const u16* __restrict__ Bt,
    const float* __restrict__ bias, float* __restrict__ C)
{
    __shared__ u16 smem[2 * 12288];   // [dbuf][sA(4K u16) | sB(8K u16)] = 48KB

    const int tid = threadIdx.x;
    const int wave = tid >> 6, lane = tid & 63;
    const int mIdx = lane & 15, quad = lane >> 4;
    const int wr = wave >> 1, wc = wave & 1;   // 2x2 waves of 32x64
    // XCD-chunked swizzle: 512 blocks = 8 XCDs x 64; chunk = 8M x 8N
    const int xcd = blockIdx.x & 7, lid = blockIdx.x >> 3;
    const int m0 = (xcd * 8 + (lid >> 3)) * 64;
    const int n0 = (lid & 7) * 128;
    const int N = DIMM, K = DIMM;
    const int lr = lane >> 3, lc = lane & 7;

    f32x4 acc[2][4];
#pragma unroll
    for (int a = 0; a < 2; ++a)
#pragma unroll
        for (int b = 0; b < 4; ++b) acc[a][b] = (f32x4){0.f, 0.f, 0.f, 0.f};

    auto stage = [&](int buf, int k0) {
        u16* sA = smem + buf * 12288;
        u16* sB = sA + 4096;
#pragma unroll
        for (int j = 0; j < 2; ++j) {       // A: 64 rows
            int r0 = 16 * wave + 8 * j + lr;
            gload16(&A[(size_t)(m0 + r0) * K + k0 + 8 * (lc ^ lr)],
                    &sA[(16 * wave + 8 * j) * 64]);
        }
#pragma unroll
        for (int j = 0; j < 4; ++j) {       // B: 128 rows
            int r0 = 32 * wave + 8 * j + lr;
            gload16(&Bt[(size_t)(n0 + r0) * K + k0 + 8 * (lc ^ lr)],
                    &sB[(32 * wave + 8 * j) * 64]);
        }
    };

    stage(0, 0);
    __syncthreads();
    int cur = 0;
    for (int t = 0; t < 16; ++t) {
        if (t + 1 < 16) stage(cur ^ 1, (t + 1) * 64);
        const u16* sA = smem + cur * 12288;
        const u16* sB = sA + 4096;
#pragma unroll
        for (int ks2 = 0; ks2 < 2; ++ks2) {
            short8 af[2], bfr[4];
#pragma unroll
            for (int mt = 0; mt < 2; ++mt) {
                int Ra = 32 * wr + 16 * mt + mIdx;
                af[mt] = *(const short8*)&sA[Ra * 64 + 8 * ((ks2 * 4 + quad) ^ (Ra & 7))];
            }
#pragma unroll
            for (int nt = 0; nt < 4; ++nt) {
                int Rb = 64 * wc + 16 * nt + mIdx;
                bfr[nt] = *(const short8*)&sB[Rb * 64 + 8 * ((ks2 * 4 + quad) ^ (Rb & 7))];
            }
#pragma unroll
            for (int mt = 0; mt < 2; ++mt)
#pragma unroll
                for (int nt = 0; nt < 4; ++nt)
                    acc[mt][nt] = __builtin_amdgcn_mfma_f32_16x16x32_bf16(
                        af[mt], bfr[nt], acc[mt][nt], 0, 0, 0);
        }
        __syncthreads();
        cur ^= 1;
    }

#pragma unroll
    for (int mt = 0; mt < 2; ++mt)
#pragma unroll
        for (int r = 0; r < 4; ++r) {
            int row = m0 + 32 * wr + 16 * mt + quad * 4 + r;
#pragma unroll
            for (int nt = 0; nt < 4; ++nt) {
                int col = n0 + 64 * wc + 16 * nt + mIdx;
                C[(size_t)row * N + col] = acc[mt][nt][r] + bias[col];
            }
        }
}

// ---------------- flash attention: fragment-direct, barrier-free --------------
__global__ __launch_bounds__(256, 2) void attn_mfma(
    const u16* __restrict__ qkv, const u16* __restrict__ kp,
    const u16* __restrict__ vp, u16* __restrict__ o)
{
    __shared__ u16 sP[128 * 64];

    const int tid = threadIdx.x;
    const int wave = tid >> 6;     // 0..3
    const int lane = tid & 63;
    const int mIdx = lane & 15;
    const int quad = lane >> 4;
    const int m7 = mIdx & 7;

    // XCD-chunked swizzle (512 blocks, 8 XCDs, 64 logical blocks per XCD)
    const int bid = ((blockIdx.x & 7) << 6) | (blockIdx.x >> 3);
    const int bh = bid >> 4;          // 16 q-tiles of 128 rows per (b,h)
    const int qt = bid & 15;
    const int b = bh >> 4, h = bh & 15;
    const int q0 = qt * 128;

    // fragment bases: tile kt at +kt*4096 u16; fragment f=nb*2+c at +f*512
    const u16* kbase = kp + (size_t)bh * 32 * 4096 + lane * 8;
    const u16* vbase = vp + (size_t)bh * 32 * 4096 + lane * 8;

    // Q fragments: 2 groups of 16 rows per wave
    short8 aq[2][2];
#pragma unroll
    for (int g = 0; g < 2; ++g) {
        const u16* qrow = qkv + (size_t)b * LL * QKV_N + h * 64
                          + (size_t)(q0 + 32 * wave + 16 * g + mIdx) * QKV_N;
        aq[g][0] = *(const short8*)&qrow[quad * 8];
        aq[g][1] = *(const short8*)&qrow[32 + quad * 8];
    }

    const short8 bones = {(short)0x3F80, (short)0x3F80, (short)0x3F80, (short)0x3F80,
                          (short)0x3F80, (short)0x3F80, (short)0x3F80, (short)0x3F80};

    f32x4 Oacc[2][4];
    f32x4 lac[2];
#pragma unroll
    for (int g = 0; g < 2; ++g) {
        lac[g] = (f32x4){0.f, 0.f, 0.f, 0.f};
#pragma unroll
        for (int nb = 0; nb < 4; ++nb) Oacc[g][nb] = (f32x4){0.f, 0.f, 0.f, 0.f};
    }

    // P swizzle offsets (same proven pattern as R11/R12)
    const int o0 = 8 * (quad ^ m7);
    const int o1 = 8 * ((quad + 4) ^ m7);
    u16* sPr0 = &sP[(32 * wave + mIdx) * 64];
    u16* sPr1 = &sP[(32 * wave + 16 + mIdx) * 64];

    short8 kfA[8], kfB[8], vf[8];

    // prologue: K fragments of tile 0
#pragma unroll
    for (int f = 0; f < 8; ++f) kfA[f] = *(const short8*)&kbase[f * 512];

    auto body = [&](short8* KC, short8* KN, int kt) {
        const size_t tb = (size_t)kt * 4096;
        // V fragments for THIS tile (consumed after S^T phase)
#pragma unroll
        for (int f = 0; f < 8; ++f) vf[f] = *(const short8*)&vbase[tb + f * 512];
        // K fragments for NEXT tile (consumed next body)
        if (kt < 31) {
#pragma unroll
            for (int f = 0; f < 8; ++f) KN[f] = *(const short8*)&kbase[tb + 4096 + f * 512];
        }
        __builtin_amdgcn_sched_barrier(0);

        // ---- S^T strips: D[key][q] = mfma(A=K-frag, B=Q-frag) ----
#pragma unroll
        for (int nb = 0; nb < 4; ++nb) {
            const int pofs = (16 * nb + 4 * quad) ^ (8 * m7);
#pragma unroll
            for (int g = 0; g < 2; ++g) {
                f32x4 st = (f32x4){0.f, 0.f, 0.f, 0.f};
                st = __builtin_amdgcn_mfma_f32_16x16x32_bf16(KC[nb * 2 + 0], aq[g][0], st, 0, 0, 0);
                st = __builtin_amdgcn_mfma_f32_16x16x32_bf16(KC[nb * 2 + 1], aq[g][1], st, 0, 0, 0);
                float p0 = exp2f(st[0]), p1 = exp2f(st[1]);
                float p2 = exp2f(st[2]), p3 = exp2f(st[3]);
                uint2 wp;
                wp.x = pack_bf2(p0, p1);
                wp.y = pack_bf2(p2, p3);
                *(uint2*)&((g == 0 ? sPr0 : sPr1)[pofs]) = wp;
            }
        }
        // sP rows written and read by the same wave -> no barrier.
        short8 pa00 = *(const short8*)&sPr0[o0];
        short8 pa01 = *(const short8*)&sPr0[o1];
        short8 pa10 = *(const short8*)&sPr1[o0];
        short8 pa11 = *(const short8*)&sPr1[o1];

        // l accumulation via MFMA with all-ones B (no VALU adds, no shuffles)
        lac[0] = __builtin_amdgcn_mfma_f32_16x16x32_bf16(pa00, bones, lac[0], 0, 0, 0);
        lac[0] = __builtin_amdgcn_mfma_f32_16x16x32_bf16(pa01, bones, lac[0], 0, 0, 0);
        lac[1] = __builtin_amdgcn_mfma_f32_16x16x32_bf16(pa10, bones, lac[1], 0, 0, 0);
        lac[1] = __builtin_amdgcn_mfma_f32_16x16x32_bf16(pa11, bones, lac[1], 0, 0, 0);

        // ---- O += P @ V ----
        __builtin_amdgcn_s_setprio(1);
#pragma unroll
        for (int nb = 0; nb < 4; ++nb) {
            Oacc[0][nb] = __builtin_amdgcn_mfma_f32_16x16x32_bf16(pa00, vf[nb * 2 + 0], Oacc[0][nb], 0, 0, 0);
            Oacc[0][nb] = __builtin_amdgcn_mfma_f32_16x16x32_bf16(pa01, vf[nb * 2 + 1], Oacc[0][nb], 0, 0, 0);
            Oacc[1][nb] = __builtin_amdgcn_mfma_f32_16x16x32_bf16(pa10, vf[nb * 2 + 0], Oacc[1][nb], 0, 0, 0);
            Oacc[1][nb] = __builtin_amdgcn_mfma_f32_16x16x32_bf16(pa11, vf[nb * 2 + 1], Oacc[1][nb], 0, 0, 0);
        }
        __builtin_amdgcn_s_setprio(0);
    };

    for (int kt2 = 0; kt2 < 16; ++kt2) {
        body(kfA, kfB, 2 * kt2);
        body(kfB, kfA, 2 * kt2 + 1);
    }

    // epilogue: l for q-row quad*4+r (within group g) sits in lac[g][r] of
    // EVERY lane (all-ones B makes all columns equal) — no shuffles needed.
#pragma unroll
    for (int g = 0; g < 2; ++g)
#pragma unroll
        for (int r = 0; r < 4; ++r) {
            float linv = 1.f / lac[g][r];
            const int rowg = b * LL + q0 + 32 * wave + 16 * g + quad * 4 + r;
#pragma unroll
            for (int nb = 0; nb < 4; ++nb) {
                o[(size_t)rowg * DIMM + h * 64 + 16 * nb + mIdx] =
                    f2bf(Oacc[g][nb][r] * linv);
            }
        }
}

extern "C" void kernel_launch(void* const* d_in, const int* in_sizes, int n_in,
                              void* d_out, int out_size, void* d_ws, size_t ws_size,
                              hipStream_t stream) {
    const float* x       = (const float*)d_in[0];
    const float* pe      = (const float*)d_in[1];
    const float* w_qkv   = (const float*)d_in[2];
    const float* q_scale = (const float*)d_in[3];
    const float* k_scale = (const float*)d_in[4];
    const float* w_proj  = (const float*)d_in[5];
    const float* b_proj  = (const float*)d_in[6];
    float* out = (float*)d_out;

    char* ws = (char*)d_ws;
    u16* qkv    = (u16*)ws;  ws += (size_t)4096 * 3072 * 2;
    u16* o      = (u16*)ws;  ws += (size_t)4096 * 1024 * 2;
    u16* xb     = (u16*)ws;  ws += (size_t)4096 * 1024 * 2;   // A-fragment-packed
    u16* wqkvt  = (u16*)ws;  ws += (size_t)3072 * 1024 * 2;   // B-fragment-packed
    u16* wprojt = (u16*)ws;  ws += (size_t)1024 * 1024 * 2;   // row-major [N][K]
    u16* kpack  = (u16*)ws;  ws += (size_t)32 * 32 * 4096 * 2;   // 8.4 MB
    u16* vpack  = (u16*)ws;  ws += (size_t)32 * 32 * 4096 * 2;   // 8.4 MB

    // 0. conversions (x and w_qkv emit MFMA-fragment-packed layouts)
    convx<<<(4096 * 1024) / (256 * 8), 256, 0, stream>>>(x, xb);
    convt<<<dim3(1024 / 64, QKV_N / 64), 256, 0, stream>>>(w_qkv, wqkvt, DIMM, QKV_N, 1);
    convt<<<dim3(1024 / 64, 1024 / 64), 256, 0, stream>>>(w_proj, wprojt, DIMM, DIMM, 0);

    // 1. QKV projection, one kernel per region (R8 ablation + XCD balance)
    gemm_qkv_r<0><<<256, 256, 0, stream>>>(xb, wqkvt, qkv, kpack, vpack, pe, q_scale, k_scale);
    gemm_qkv_r<1><<<256, 256, 0, stream>>>(xb, wqkvt, qkv, kpack, vpack, pe, q_scale, k_scale);
    gemm_qkv_r<2><<<256, 256, 0, stream>>>(xb, wqkvt, qkv, kpack, vpack, pe, q_scale, k_scale);

    // 2. attention (fragment-direct K/V, barrier-free)
    attn_mfma<<<BB * HH * (LL / 128), 256, 0, stream>>>(qkv, kpack, vpack, o);

    // 3. output projection + bias (f32 out)
    gemm_proj<<<512, 256, 0, stream>>>(o, wprojt, b_proj, out);
}